// Round 2
// baseline (1414.470 us; speedup 1.0000x reference)
//
#include <hip/hip_runtime.h>
#include <hip/hip_bf16.h>

#define BD 4
#define CD 96
#define OD 96
#define HD 128
#define WD 128
#define HWD (HD*WD)          // 16384

// ---------------------------------------------------------------------------
// Repack weights (fp32 OIHW) into GEMM-friendly fp32 layouts:
//   dconv_wT[(c*9+tap)*96 + o]   from dconv_w[(o*96+c)*9+tap]
//   off_wT [(c*9+tap)*18 + j]    from off_w [(j*96+c)*9+tap]
//   def_wT [(k*96+c)*96 + o]     from def_w [(o*96+c)*9+k]
// ---------------------------------------------------------------------------
__global__ void k_repack(const float* __restrict__ dconv_w,
                         const float* __restrict__ off_w,
                         const float* __restrict__ def_w,
                         float* __restrict__ dconv_wT,
                         float* __restrict__ off_wT,
                         float* __restrict__ def_wT) {
    int t = blockIdx.x * blockDim.x + threadIdx.x;
    if (t < 96*9*96) {            // dconv
        int o = t % 96; int r = t / 96; int tap = r % 9; int c = r / 9;
        dconv_wT[t] = dconv_w[(o*96+c)*9 + tap];
    }
    if (t < 96*9*18) {            // offset conv
        int j = t % 18; int r = t / 18; int tap = r % 9; int c = r / 9;
        off_wT[t] = off_w[(j*96+c)*9 + tap];
    }
    if (t < 9*96*96) {            // deform einsum
        int o = t % 96; int r = t / 96; int c = r % 96; int k = r / 96;
        def_wT[t] = def_w[(o*96+c)*9 + k];
    }
}

// ---------------------------------------------------------------------------
// Kernel 1: x3 = x + relu(conv3x3 dil=2 pad=2 (x))  -> NHWC fp32
// Block: 256 thr = 16 pixel-groups (4 px each) x 16 o-lanes (6 o each).
// Block tile: 64 consecutive pixels in one row.
// ---------------------------------------------------------------------------
__global__ __launch_bounds__(256) void k_conv1(const float* __restrict__ x,
                                               const float* __restrict__ wT,
                                               const float* __restrict__ bias,
                                               float* __restrict__ x3) {
    int pix0 = blockIdx.x * 64;
    int b   = pix0 / HWD;
    int hw0 = pix0 % HWD;
    int h   = hw0 / WD;
    int g   = threadIdx.x >> 4;          // pixel group 0..15
    int oi  = threadIdx.x & 15;          // o-lane
    int w0  = (hw0 % WD) + (g << 2);     // first of 4 pixels

    float acc[4][6];
    float bj[6];
    #pragma unroll
    for (int j = 0; j < 6; j++) bj[j] = bias[oi*6 + j];
    #pragma unroll
    for (int p = 0; p < 4; p++)
        #pragma unroll
        for (int j = 0; j < 6; j++) acc[p][j] = bj[j];

    const float* xb = x + (size_t)b * CD * HWD;
    for (int c = 0; c < CD; c++) {
        const float* xc = xb + c * HWD;
        float xv[9][4];
        #pragma unroll
        for (int t = 0; t < 9; t++) {
            int y = h + (t/3)*2 - 2;
            bool vy = (unsigned)y < HD;
            #pragma unroll
            for (int p = 0; p < 4; p++) {
                int xx = w0 + p + (t%3)*2 - 2;
                xv[t][p] = (vy && (unsigned)xx < WD) ? xc[y*WD + xx] : 0.f;
            }
        }
        const float* wc = wT + c*9*96 + oi*6;
        #pragma unroll
        for (int t = 0; t < 9; t++) {
            const float2* wp = (const float2*)(wc + t*96);
            float2 w01 = wp[0], w23 = wp[1], w45 = wp[2];
            float wv[6] = {w01.x, w01.y, w23.x, w23.y, w45.x, w45.y};
            #pragma unroll
            for (int p = 0; p < 4; p++)
                #pragma unroll
                for (int j = 0; j < 6; j++) acc[p][j] += xv[t][p] * wv[j];
        }
    }

    #pragma unroll
    for (int p = 0; p < 4; p++) {
        int hw = hw0 + (g << 2) + p;
        float* outp = x3 + ((size_t)b * HWD + hw) * 96 + oi*6;
        #pragma unroll
        for (int j = 0; j < 6; j++) {
            int o = oi*6 + j;
            float xo = xb[(size_t)o * HWD + hw];
            outp[j] = xo + fmaxf(acc[p][j], 0.f);
        }
    }
}

// ---------------------------------------------------------------------------
// Kernel 2: offset = conv3x3 pad=1 (x3), 18 out channels -> offs[pix][18] fp32
// One thread per pixel, all 18 outputs in registers.
// ---------------------------------------------------------------------------
__global__ __launch_bounds__(256) void k_conv2(const float* __restrict__ x3,
                                               const float* __restrict__ wT,
                                               const float* __restrict__ bias,
                                               float* __restrict__ offs) {
    int pix = blockIdx.x * 256 + threadIdx.x;
    int b = pix / HWD; int hw = pix % HWD;
    int h = hw / WD, w = hw % WD;

    float acc[18];
    #pragma unroll
    for (int j = 0; j < 18; j++) acc[j] = bias[j];

    #pragma unroll
    for (int t = 0; t < 9; t++) {
        int y = h + t/3 - 1, xx = w + t%3 - 1;
        if ((unsigned)y >= HD || (unsigned)xx >= WD) continue;
        const float* xp = x3 + ((size_t)b * HWD + y*WD + xx) * 96;
        const float* wt = wT + t*18;
        for (int c = 0; c < 96; c += 4) {
            float4 v = *(const float4*)(xp + c);
            const float* wp = wt + c*9*18;
            #pragma unroll
            for (int j = 0; j < 18; j++) {
                acc[j] += v.x * wp[j]
                        + v.y * wp[162 + j]
                        + v.z * wp[324 + j]
                        + v.w * wp[486 + j];
            }
        }
    }
    float* op = offs + (size_t)pix * 18;
    #pragma unroll
    for (int j = 0; j < 18; j++) op[j] = acc[j];
}

// ---------------------------------------------------------------------------
// Kernel 3: deformable bilinear sample of x3 + einsum with def_w + bias.
// Block: 256 thr, 16 pixels. LDS: samp[16][868].
// ---------------------------------------------------------------------------
__global__ __launch_bounds__(256) void k_deform(const float* __restrict__ x3,
                                                const float* __restrict__ offs,
                                                const float* __restrict__ wT,
                                                const float* __restrict__ bias,
                                                float* __restrict__ out) {
    __shared__ float samp[16][868];
    __shared__ float tinfo[144][4];

    int pix0 = blockIdx.x * 16;
    int b = pix0 / HWD; int hw0 = pix0 % HWD;
    int tid = threadIdx.x;

    // Phase A: per (pixel, tap) bilinear setup
    if (tid < 144) {
        int px = tid / 9, tap = tid % 9;
        int hw = hw0 + px; int h = hw / WD, w = hw % WD;
        const float* op = offs + ((size_t)b * HWD + hw) * 18 + tap*2;
        float dy = op[0], dx = op[1];
        float py  = (float)(h + tap/3 - 1) + dy;
        float pxf = (float)(w + tap%3 - 1) + dx;
        float y0 = floorf(py), x0 = floorf(pxf);
        tinfo[tid][0] = y0; tinfo[tid][1] = x0;
        tinfo[tid][2] = py - y0; tinfo[tid][3] = pxf - x0;
    }
    __syncthreads();

    int pl = tid >> 4;        // pixel 0..15
    int ci = tid & 15;        // channel-chunk lane
    const float* xb = x3 + (size_t)b * HWD * 96;

    // Phase B: gather + lerp 96 channels per (pixel, tap)
    #pragma unroll 1
    for (int tap = 0; tap < 9; tap++) {
        int it = pl*9 + tap;
        float y0f = tinfo[it][0], x0f = tinfo[it][1];
        float wy = tinfo[it][2], wx = tinfo[it][3];
        int y0 = (int)y0f, x0 = (int)x0f;
        int y1 = y0 + 1, x1 = x0 + 1;
        bool vy0 = (unsigned)y0 < HD, vy1 = (unsigned)y1 < HD;
        bool vx0 = (unsigned)x0 < WD, vx1 = (unsigned)x1 < WD;
        float f00 = (vy0 && vx0) ? (1.f-wy)*(1.f-wx) : 0.f;
        float f01 = (vy0 && vx1) ? (1.f-wy)*wx       : 0.f;
        float f10 = (vy1 && vx0) ? wy*(1.f-wx)       : 0.f;
        float f11 = (vy1 && vx1) ? wy*wx             : 0.f;
        int yc0 = min(max(y0,0),HD-1), yc1 = min(max(y1,0),HD-1);
        int xc0 = min(max(x0,0),WD-1), xc1 = min(max(x1,0),WD-1);
        const float* p00 = xb + (yc0*WD + xc0)*96;
        const float* p01 = xb + (yc0*WD + xc1)*96;
        const float* p10 = xb + (yc1*WD + xc0)*96;
        const float* p11 = xb + (yc1*WD + xc1)*96;
        int c0 = ci*6;
        #pragma unroll
        for (int m = 0; m < 3; m++) {
            float2 v00 = *(const float2*)(p00 + c0 + 2*m);
            float2 v01 = *(const float2*)(p01 + c0 + 2*m);
            float2 v10 = *(const float2*)(p10 + c0 + 2*m);
            float2 v11 = *(const float2*)(p11 + c0 + 2*m);
            samp[pl][tap*96 + c0 + 2*m]     = f00*v00.x + f01*v01.x + f10*v10.x + f11*v11.x;
            samp[pl][tap*96 + c0 + 2*m + 1] = f00*v00.y + f01*v01.y + f10*v10.y + f11*v11.y;
        }
    }
    __syncthreads();

    // Phase C: out[o] = sum_{k,c} samp[k*96+c] * wT[(k*96+c)*96+o] + bias
    float acc[6];
    #pragma unroll
    for (int j = 0; j < 6; j++) acc[j] = bias[ci*6 + j];
    const float* sp = samp[pl];
    for (int kc = 0; kc < 864; kc++) {
        float s = sp[kc];
        const float2* wp = (const float2*)(wT + kc*96 + ci*6);
        float2 a0 = wp[0], a1 = wp[1], a2 = wp[2];
        acc[0] += s*a0.x; acc[1] += s*a0.y;
        acc[2] += s*a1.x; acc[3] += s*a1.y;
        acc[4] += s*a2.x; acc[5] += s*a2.y;
    }
    int hw = hw0 + pl;
    float* ob = out + (size_t)b * OD * HWD + hw;
    #pragma unroll
    for (int j = 0; j < 6; j++)
        ob[(size_t)(ci*6 + j) * HWD] = acc[j];
}

// ---------------------------------------------------------------------------
// Workspace layout (bytes):
//   x3      : 0          .. 25165824   (B*HW*96 fp32, NHWC)
//   offs    : 25165824   .. 29884416   (B*HW*18 fp32)
//   dconv_wT: 29884416   .. 30216192
//   off_wT  : 30216192   .. 30278400
//   def_wT  : 30278400   .. 30610176
// ---------------------------------------------------------------------------
extern "C" void kernel_launch(void* const* d_in, const int* in_sizes, int n_in,
                              void* d_out, int out_size, void* d_ws, size_t ws_size,
                              hipStream_t stream) {
    const float* x       = (const float*)d_in[0];
    const float* dconv_w = (const float*)d_in[1];
    const float* dconv_b = (const float*)d_in[2];
    const float* off_w   = (const float*)d_in[3];
    const float* off_b   = (const float*)d_in[4];
    const float* def_w   = (const float*)d_in[5];
    const float* def_b   = (const float*)d_in[6];
    float* out = (float*)d_out;

    char* ws = (char*)d_ws;
    float* x3       = (float*)(ws);
    float* offs     = (float*)(ws + 25165824);
    float* dconv_wT = (float*)(ws + 29884416);
    float* off_wT   = (float*)(ws + 30216192);
    float* def_wT   = (float*)(ws + 30278400);

    k_repack<<<324, 256, 0, stream>>>(dconv_w, off_w, def_w, dconv_wT, off_wT, def_wT);
    k_conv1<<<(BD*HWD)/64, 256, 0, stream>>>(x, dconv_wT, dconv_b, x3);
    k_conv2<<<(BD*HWD)/256, 256, 0, stream>>>(x3, off_wT, off_b, offs);
    k_deform<<<(BD*HWD)/16, 256, 0, stream>>>(x3, offs, def_wT, def_b, out);
}

// Round 3
// 602.255 us; speedup vs baseline: 2.3486x; 2.3486x over previous
//
#include <hip/hip_runtime.h>
#include <hip/hip_bf16.h>

#define BD 4
#define CD 96
#define OD 96
#define HD 128
#define WD 128
#define HWD (HD*WD)          // 16384

typedef __attribute__((ext_vector_type(8))) short bfrag;   // 8 bf16 (4 VGPRs)
typedef __attribute__((ext_vector_type(4))) float ffrag;   // 4 fp32 acc
typedef __attribute__((ext_vector_type(4))) short s4v;     // 4 bf16 (8 B)

__device__ __forceinline__ short f2bs(float f) {
    __hip_bfloat16 h = __float2bfloat16(f);
    return *reinterpret_cast<short*>(&h);
}

// ---------------------------------------------------------------------------
// Repack weights:
//   dconv_wT[(c*9+tap)*96 + o]  (fp32)      from dconv_w[(o*96+c)*9+tap]
//   off_wT [(c*9+tap)*18 + j]   (fp32)      from off_w [(j*96+c)*9+tap]
//   wB: def_w in bf16 MFMA B-fragment order:
//     wB[((s*6+nt)*64 + l)*8 + j] = B[k=32s+(l>>4)*8+j][o=16nt+(l&15)]
//     where B[k][o] = def_w[(o*96 + k%96)*9 + k/96]   (kc = tap*96 + c)
// ---------------------------------------------------------------------------
__global__ void k_repack(const float* __restrict__ dconv_w,
                         const float* __restrict__ off_w,
                         const float* __restrict__ def_w,
                         float* __restrict__ dconv_wT,
                         float* __restrict__ off_wT,
                         short* __restrict__ wB) {
    int t = blockIdx.x * blockDim.x + threadIdx.x;
    if (t < 96*9*96) {            // dconv
        int o = t % 96; int r = t / 96; int tap = r % 9; int c = r / 9;
        dconv_wT[t] = dconv_w[(o*96+c)*9 + tap];
    }
    if (t < 96*9*18) {            // offset conv
        int j = t % 18; int r = t / 18; int tap = r % 9; int c = r / 9;
        off_wT[t] = off_w[(j*96+c)*9 + tap];
    }
    if (t < 82944) {              // deform einsum, MFMA B layout (82944 = 864*96)
        int j = t & 7; int l = (t >> 3) & 63; int tile = t >> 9;
        int s = tile / 6, nt = tile % 6;
        int k = 32*s + (l >> 4)*8 + j;
        int o = 16*nt + (l & 15);
        int c = k % 96, tap = k / 96;
        wB[t] = f2bs(def_w[(o*96 + c)*9 + tap]);
    }
}

// ---------------------------------------------------------------------------
// Kernel 1: x3 = x + relu(conv3x3 dil=2 pad=2 (x))  -> NHWC fp32
// ---------------------------------------------------------------------------
__global__ __launch_bounds__(256) void k_conv1(const float* __restrict__ x,
                                               const float* __restrict__ wT,
                                               const float* __restrict__ bias,
                                               float* __restrict__ x3) {
    int pix0 = blockIdx.x * 64;
    int b   = pix0 / HWD;
    int hw0 = pix0 % HWD;
    int h   = hw0 / WD;
    int g   = threadIdx.x >> 4;
    int oi  = threadIdx.x & 15;
    int w0  = (hw0 % WD) + (g << 2);

    float acc[4][6];
    float bj[6];
    #pragma unroll
    for (int j = 0; j < 6; j++) bj[j] = bias[oi*6 + j];
    #pragma unroll
    for (int p = 0; p < 4; p++)
        #pragma unroll
        for (int j = 0; j < 6; j++) acc[p][j] = bj[j];

    const float* xb = x + (size_t)b * CD * HWD;
    for (int c = 0; c < CD; c++) {
        const float* xc = xb + c * HWD;
        float xv[9][4];
        #pragma unroll
        for (int t = 0; t < 9; t++) {
            int y = h + (t/3)*2 - 2;
            bool vy = (unsigned)y < HD;
            #pragma unroll
            for (int p = 0; p < 4; p++) {
                int xx = w0 + p + (t%3)*2 - 2;
                xv[t][p] = (vy && (unsigned)xx < WD) ? xc[y*WD + xx] : 0.f;
            }
        }
        const float* wc = wT + c*9*96 + oi*6;
        #pragma unroll
        for (int t = 0; t < 9; t++) {
            const float2* wp = (const float2*)(wc + t*96);
            float2 w01 = wp[0], w23 = wp[1], w45 = wp[2];
            float wv[6] = {w01.x, w01.y, w23.x, w23.y, w45.x, w45.y};
            #pragma unroll
            for (int p = 0; p < 4; p++)
                #pragma unroll
                for (int j = 0; j < 6; j++) acc[p][j] += xv[t][p] * wv[j];
        }
    }

    #pragma unroll
    for (int p = 0; p < 4; p++) {
        int hw = hw0 + (g << 2) + p;
        float* outp = x3 + ((size_t)b * HWD + hw) * 96 + oi*6;
        #pragma unroll
        for (int j = 0; j < 6; j++) {
            int o = oi*6 + j;
            float xo = xb[(size_t)o * HWD + hw];
            outp[j] = xo + fmaxf(acc[p][j], 0.f);
        }
    }
}

// ---------------------------------------------------------------------------
// Kernel 2: offset = conv3x3 pad=1 (x3) -> offs[pix][18] fp32
// ---------------------------------------------------------------------------
__global__ __launch_bounds__(256) void k_conv2(const float* __restrict__ x3,
                                               const float* __restrict__ wT,
                                               const float* __restrict__ bias,
                                               float* __restrict__ offs) {
    int pix = blockIdx.x * 256 + threadIdx.x;
    int b = pix / HWD; int hw = pix % HWD;
    int h = hw / WD, w = hw % WD;

    float acc[18];
    #pragma unroll
    for (int j = 0; j < 18; j++) acc[j] = bias[j];

    #pragma unroll
    for (int t = 0; t < 9; t++) {
        int y = h + t/3 - 1, xx = w + t%3 - 1;
        if ((unsigned)y >= HD || (unsigned)xx >= WD) continue;
        const float* xp = x3 + ((size_t)b * HWD + y*WD + xx) * 96;
        const float* wt = wT + t*18;
        for (int c = 0; c < 96; c += 4) {
            float4 v = *(const float4*)(xp + c);
            const float* wp = wt + c*9*18;
            #pragma unroll
            for (int j = 0; j < 18; j++) {
                acc[j] += v.x * wp[j]
                        + v.y * wp[162 + j]
                        + v.z * wp[324 + j]
                        + v.w * wp[486 + j];
            }
        }
    }
    float* op = offs + (size_t)pix * 18;
    #pragma unroll
    for (int j = 0; j < 18; j++) op[j] = acc[j];
}

// ---------------------------------------------------------------------------
// Kernel 3: deformable sample + MFMA einsum.
// Block: 256 thr (4 waves), 32 pixels.
// Phase B: gather+lerp x3 (fp32 NHWC) -> samp bf16 LDS [32][872 stride].
// Phase C: out[32][96] = samp[32][864] x wB[864][96] via mfma 16x16x32 bf16.
//   Wave w: mt = w>>1 (pixel half), nt = (w&1)*3 .. +2 (o tiles), K = 27 steps.
// ---------------------------------------------------------------------------
__global__ __launch_bounds__(256) void k_deform(const float* __restrict__ x3,
                                                const float* __restrict__ offs,
                                                const short* __restrict__ wB,
                                                const float* __restrict__ bias,
                                                float* __restrict__ out) {
    __shared__ short samp[32 * 872];   // 55808 B, rows 16B-aligned

    int pix0 = blockIdx.x * 32;
    int b = pix0 / HWD; int hw0 = pix0 % HWD;
    int tid = threadIdx.x;

    // ---- Phase B: gather + bilinear lerp, write bf16 to LDS ----
    int pl = tid >> 3;          // pixel 0..31
    int ci = tid & 7;           // channel lane: 12 ch each
    int hw = hw0 + pl;
    int h = hw / WD, w = hw % WD;
    const float* xb = x3 + (size_t)b * HWD * 96;
    const float* opx = offs + ((size_t)b * HWD + hw) * 18;
    int c0 = ci * 12;

    #pragma unroll 1
    for (int tap = 0; tap < 9; tap++) {
        float dy = opx[tap*2], dx = opx[tap*2 + 1];
        float py  = (float)(h + tap/3 - 1) + dy;
        float pxf = (float)(w + tap%3 - 1) + dx;
        float y0f = floorf(py), x0f = floorf(pxf);
        float wy = py - y0f, wx = pxf - x0f;
        int y0 = (int)y0f, x0 = (int)x0f;
        int y1 = y0 + 1, x1 = x0 + 1;
        bool vy0 = (unsigned)y0 < HD, vy1 = (unsigned)y1 < HD;
        bool vx0 = (unsigned)x0 < WD, vx1 = (unsigned)x1 < WD;
        float f00 = (vy0 && vx0) ? (1.f-wy)*(1.f-wx) : 0.f;
        float f01 = (vy0 && vx1) ? (1.f-wy)*wx       : 0.f;
        float f10 = (vy1 && vx0) ? wy*(1.f-wx)       : 0.f;
        float f11 = (vy1 && vx1) ? wy*wx             : 0.f;
        int yc0 = min(max(y0,0),HD-1), yc1 = min(max(y1,0),HD-1);
        int xc0 = min(max(x0,0),WD-1), xc1 = min(max(x1,0),WD-1);
        const float* p00 = xb + (yc0*WD + xc0)*96 + c0;
        const float* p01 = xb + (yc0*WD + xc1)*96 + c0;
        const float* p10 = xb + (yc1*WD + xc0)*96 + c0;
        const float* p11 = xb + (yc1*WD + xc1)*96 + c0;
        short* sp = samp + pl*872 + tap*96 + c0;
        #pragma unroll
        for (int m = 0; m < 3; m++) {
            float4 v00 = *(const float4*)(p00 + 4*m);
            float4 v01 = *(const float4*)(p01 + 4*m);
            float4 v10 = *(const float4*)(p10 + 4*m);
            float4 v11 = *(const float4*)(p11 + 4*m);
            float r0 = f00*v00.x + f01*v01.x + f10*v10.x + f11*v11.x;
            float r1 = f00*v00.y + f01*v01.y + f10*v10.y + f11*v11.y;
            float r2 = f00*v00.z + f01*v01.z + f10*v10.z + f11*v11.z;
            float r3 = f00*v00.w + f01*v01.w + f10*v10.w + f11*v11.w;
            s4v pk = { f2bs(r0), f2bs(r1), f2bs(r2), f2bs(r3) };
            *(s4v*)(sp + 4*m) = pk;
        }
    }
    __syncthreads();

    // ---- Phase C: MFMA GEMM ----
    int l  = tid & 63;
    int wv = tid >> 6;
    int mt = wv >> 1;               // pixel tile 0/1
    int ntb = (wv & 1) * 3;         // first o-tile
    int q = l >> 4, mr = l & 15;

    const short* arow = samp + (16*mt + mr)*872 + q*8;
    ffrag acc0 = {0.f,0.f,0.f,0.f}, acc1 = acc0, acc2 = acc0;

    #pragma unroll 3
    for (int s = 0; s < 27; s++) {
        bfrag a  = *(const bfrag*)(arow + 32*s);
        const short* wb = wB + ((size_t)(s*6 + ntb)*64 + l)*8;
        bfrag b0 = *(const bfrag*)(wb);
        bfrag b1 = *(const bfrag*)(wb + 512);
        bfrag b2 = *(const bfrag*)(wb + 1024);
        acc0 = __builtin_amdgcn_mfma_f32_16x16x32_bf16(a, b0, acc0, 0, 0, 0);
        acc1 = __builtin_amdgcn_mfma_f32_16x16x32_bf16(a, b1, acc1, 0, 0, 0);
        acc2 = __builtin_amdgcn_mfma_f32_16x16x32_bf16(a, b2, acc2, 0, 0, 0);
    }

    // store: lane l holds D[m = q*4+r][o = 16*nt + mr] for each tile
    ffrag accs[3] = {acc0, acc1, acc2};
    #pragma unroll
    for (int t = 0; t < 3; t++) {
        int o = 16*(ntb + t) + mr;
        float bo = bias[o];
        float* ob = out + ((size_t)b * OD + o) * HWD + hw0 + 16*mt + q*4;
        #pragma unroll
        for (int r = 0; r < 4; r++) ob[r] = accs[t][r] + bo;
    }
}

// ---------------------------------------------------------------------------
// Workspace layout (bytes):
//   x3      : 0          .. 25165824   (B*HW*96 fp32, NHWC)
//   offs    : 25165824   .. 29884416   (B*HW*18 fp32)
//   dconv_wT: 29884416   .. 30216192
//   off_wT  : 30216192   .. 30278400
//   wB      : 30278400   .. 30444288   (864*96 bf16, MFMA B layout)
// ---------------------------------------------------------------------------
extern "C" void kernel_launch(void* const* d_in, const int* in_sizes, int n_in,
                              void* d_out, int out_size, void* d_ws, size_t ws_size,
                              hipStream_t stream) {
    const float* x       = (const float*)d_in[0];
    const float* dconv_w = (const float*)d_in[1];
    const float* dconv_b = (const float*)d_in[2];
    const float* off_w   = (const float*)d_in[3];
    const float* off_b   = (const float*)d_in[4];
    const float* def_w   = (const float*)d_in[5];
    const float* def_b   = (const float*)d_in[6];
    float* out = (float*)d_out;

    char* ws = (char*)d_ws;
    float* x3       = (float*)(ws);
    float* offs     = (float*)(ws + 25165824);
    float* dconv_wT = (float*)(ws + 29884416);
    float* off_wT   = (float*)(ws + 30216192);
    short* wB       = (short*)(ws + 30278400);

    k_repack<<<324, 256, 0, stream>>>(dconv_w, off_w, def_w, dconv_wT, off_wT, wB);
    k_conv1<<<(BD*HWD)/64, 256, 0, stream>>>(x, dconv_wT, dconv_b, x3);
    k_conv2<<<(BD*HWD)/256, 256, 0, stream>>>(x3, off_wT, off_b, offs);
    k_deform<<<(BD*HWD)/32, 256, 0, stream>>>(x3, offs, wB, def_b, out);
}

// Round 4
// 321.585 us; speedup vs baseline: 4.3984x; 1.8728x over previous
//
#include <hip/hip_runtime.h>
#include <hip/hip_bf16.h>

#define BD 4
#define CD 96
#define OD 96
#define HD 128
#define WD 128
#define HWD (HD*WD)          // 16384

#define COLS 36              // staged cols: w0-2 .. w0+33
#define CSTR 104             // shorts per (row,col) pixel: 96 + 8 pad

typedef __attribute__((ext_vector_type(8))) short bfrag;   // 8 bf16 (4 VGPRs)
typedef __attribute__((ext_vector_type(4))) float ffrag;   // 4 fp32 acc
typedef __attribute__((ext_vector_type(4))) short s4v;     // 4 bf16 (8 B)

__device__ __forceinline__ short f2bs(float f) {
    __hip_bfloat16 h = __float2bfloat16(f);
    return *reinterpret_cast<short*>(&h);
}

// ---------------------------------------------------------------------------
// Repack weights:
//   wB1: dconv_w -> bf16 MFMA B-frag order (k = tap*96+c, 864x96)
//   off_wT[(c*9+tap)*18 + j] (fp32)  from off_w[(j*96+c)*9+tap]
//   wB : def_w  -> bf16 MFMA B-frag order (k = tap*96+c, 864x96)
//   B-frag order: w[((s*6+nt)*64 + l)*8 + j] = B[k=32s+(l>>4)*8+j][o=16nt+(l&15)]
// ---------------------------------------------------------------------------
__global__ void k_repack(const float* __restrict__ dconv_w,
                         const float* __restrict__ off_w,
                         const float* __restrict__ def_w,
                         short* __restrict__ wB1,
                         float* __restrict__ off_wT,
                         short* __restrict__ wB) {
    int t = blockIdx.x * blockDim.x + threadIdx.x;
    if (t < 96*9*18) {            // offset conv
        int j = t % 18; int r = t / 18; int tap = r % 9; int c = r / 9;
        off_wT[t] = off_w[(j*96+c)*9 + tap];
    }
    if (t < 82944) {              // 864*96, MFMA B layouts
        int j = t & 7; int l = (t >> 3) & 63; int tile = t >> 9;
        int s = tile / 6, nt = tile % 6;
        int k = 32*s + (l >> 4)*8 + j;
        int o = 16*nt + (l & 15);
        int c = k % 96, tap = k / 96;
        wB1[t] = f2bs(dconv_w[(o*96 + c)*9 + tap]);
        wB[t]  = f2bs(def_w [(o*96 + c)*9 + tap]);
    }
}

// ---------------------------------------------------------------------------
// Kernel 1 (MFMA): x3 = x + relu(conv3x3 dil=2 pad=2 (x)) -> NHWC fp32
// Block: 256 thr (4 waves), 32 consecutive pixels in one row.
// Phase A: stage x-tile [3 dilated rows][36 cols][96 ch] bf16 -> LDS (zero OOB)
// Phase C: D[32 px][96 o] = A[32][864] x wB1[864][96], taps resolved as
//          (row, col-shift) address offsets into the x-tile.
// ---------------------------------------------------------------------------
__global__ __launch_bounds__(256) void k_conv1(const float* __restrict__ x,
                                               const short* __restrict__ wB,
                                               const float* __restrict__ bias,
                                               float* __restrict__ x3) {
    __shared__ short xt[3 * COLS * CSTR];   // 22464 B

    int pix0 = blockIdx.x * 32;
    int b = pix0 / HWD; int hw0 = pix0 % HWD;
    int h = hw0 / WD, w0 = hw0 % WD;
    int tid = threadIdx.x;
    const float* xb = x + (size_t)b * CD * HWD;

    // ---- Phase A: stage raw tile ----
    for (int e = tid; e < 3*96*COLS; e += 256) {
        int col = e % COLS; int rc = e / COLS;
        int ro = rc / 96, c = rc % 96;
        int y  = h + ro*2 - 2;
        int xx = w0 - 2 + col;
        float v = ((unsigned)y < HD && (unsigned)xx < WD) ? xb[c*HWD + y*WD + xx] : 0.f;
        xt[(ro*COLS + col)*CSTR + c] = f2bs(v);
    }
    __syncthreads();

    // ---- Phase C: MFMA GEMM ----
    int l  = tid & 63;
    int wv = tid >> 6;
    int mt = wv >> 1;               // pixel tile 0/1
    int ntb = (wv & 1) * 3;         // first o-tile
    int q = l >> 4, mr = l & 15;
    int px = 16*mt + mr;            // A-row = pixel

    ffrag acc0 = {0.f,0.f,0.f,0.f}, acc1 = acc0, acc2 = acc0;

    #pragma unroll 3
    for (int s = 0; s < 27; s++) {
        int tap = s / 3;                 // k = tap*96 + c ordering
        int ro  = tap / 3;
        int dxi = (tap % 3) * 2;         // col shift 0,2,4 (origin w0-2)
        int c0  = (s % 3) * 32 + q*8;
        bfrag a = *(const bfrag*)(xt + (ro*COLS + px + dxi)*CSTR + c0);
        const short* wb = wB + ((size_t)(s*6 + ntb)*64 + l)*8;
        bfrag b0 = *(const bfrag*)(wb);
        bfrag b1 = *(const bfrag*)(wb + 512);
        bfrag b2 = *(const bfrag*)(wb + 1024);
        acc0 = __builtin_amdgcn_mfma_f32_16x16x32_bf16(a, b0, acc0, 0, 0, 0);
        acc1 = __builtin_amdgcn_mfma_f32_16x16x32_bf16(a, b1, acc1, 0, 0, 0);
        acc2 = __builtin_amdgcn_mfma_f32_16x16x32_bf16(a, b2, acc2, 0, 0, 0);
    }

    // ---- Epilogue: x3 = x + relu(conv + bias), NHWC fp32 ----
    // lane holds D[px = 16*mt + q*4 + r][o = 16*(ntb+t) + mr]
    ffrag accs[3] = {acc0, acc1, acc2};
    int hwb = hw0 + 16*mt + q*4;
    float* opb = x3 + ((size_t)b * HWD + hwb) * 96;
    #pragma unroll
    for (int t = 0; t < 3; t++) {
        int o = 16*(ntb + t) + mr;
        float bo = bias[o];
        float4 xr = *(const float4*)(xb + (size_t)o * HWD + hwb);
        float* op = opb + o;
        op[0]   = xr.x + fmaxf(accs[t][0] + bo, 0.f);
        op[96]  = xr.y + fmaxf(accs[t][1] + bo, 0.f);
        op[192] = xr.z + fmaxf(accs[t][2] + bo, 0.f);
        op[288] = xr.w + fmaxf(accs[t][3] + bo, 0.f);
    }
}

// ---------------------------------------------------------------------------
// Kernel 2: offset = conv3x3 pad=1 (x3) -> offs[pix][18] fp32
// ---------------------------------------------------------------------------
__global__ __launch_bounds__(256) void k_conv2(const float* __restrict__ x3,
                                               const float* __restrict__ wT,
                                               const float* __restrict__ bias,
                                               float* __restrict__ offs) {
    int pix = blockIdx.x * 256 + threadIdx.x;
    int b = pix / HWD; int hw = pix % HWD;
    int h = hw / WD, w = hw % WD;

    float acc[18];
    #pragma unroll
    for (int j = 0; j < 18; j++) acc[j] = bias[j];

    #pragma unroll
    for (int t = 0; t < 9; t++) {
        int y = h + t/3 - 1, xx = w + t%3 - 1;
        if ((unsigned)y >= HD || (unsigned)xx >= WD) continue;
        const float* xp = x3 + ((size_t)b * HWD + y*WD + xx) * 96;
        const float* wt = wT + t*18;
        for (int c = 0; c < 96; c += 4) {
            float4 v = *(const float4*)(xp + c);
            const float* wp = wt + c*9*18;
            #pragma unroll
            for (int j = 0; j < 18; j++) {
                acc[j] += v.x * wp[j]
                        + v.y * wp[162 + j]
                        + v.z * wp[324 + j]
                        + v.w * wp[486 + j];
            }
        }
    }
    float* op = offs + (size_t)pix * 18;
    #pragma unroll
    for (int j = 0; j < 18; j++) op[j] = acc[j];
}

// ---------------------------------------------------------------------------
// Kernel 3: deformable sample + MFMA einsum (unchanged from R3).
// ---------------------------------------------------------------------------
__global__ __launch_bounds__(256) void k_deform(const float* __restrict__ x3,
                                                const float* __restrict__ offs,
                                                const short* __restrict__ wB,
                                                const float* __restrict__ bias,
                                                float* __restrict__ out) {
    __shared__ short samp[32 * 872];   // 55808 B

    int pix0 = blockIdx.x * 32;
    int b = pix0 / HWD; int hw0 = pix0 % HWD;
    int tid = threadIdx.x;

    int pl = tid >> 3;          // pixel 0..31
    int ci = tid & 7;           // channel lane: 12 ch each
    int hw = hw0 + pl;
    int h = hw / WD, w = hw % WD;
    const float* xb = x3 + (size_t)b * HWD * 96;
    const float* opx = offs + ((size_t)b * HWD + hw) * 18;
    int c0 = ci * 12;

    #pragma unroll 1
    for (int tap = 0; tap < 9; tap++) {
        float dy = opx[tap*2], dx = opx[tap*2 + 1];
        float py  = (float)(h + tap/3 - 1) + dy;
        float pxf = (float)(w + tap%3 - 1) + dx;
        float y0f = floorf(py), x0f = floorf(pxf);
        float wy = py - y0f, wx = pxf - x0f;
        int y0 = (int)y0f, x0 = (int)x0f;
        int y1 = y0 + 1, x1 = x0 + 1;
        bool vy0 = (unsigned)y0 < HD, vy1 = (unsigned)y1 < HD;
        bool vx0 = (unsigned)x0 < WD, vx1 = (unsigned)x1 < WD;
        float f00 = (vy0 && vx0) ? (1.f-wy)*(1.f-wx) : 0.f;
        float f01 = (vy0 && vx1) ? (1.f-wy)*wx       : 0.f;
        float f10 = (vy1 && vx0) ? wy*(1.f-wx)       : 0.f;
        float f11 = (vy1 && vx1) ? wy*wx             : 0.f;
        int yc0 = min(max(y0,0),HD-1), yc1 = min(max(y1,0),HD-1);
        int xc0 = min(max(x0,0),WD-1), xc1 = min(max(x1,0),WD-1);
        const float* p00 = xb + (yc0*WD + xc0)*96 + c0;
        const float* p01 = xb + (yc0*WD + xc1)*96 + c0;
        const float* p10 = xb + (yc1*WD + xc0)*96 + c0;
        const float* p11 = xb + (yc1*WD + xc1)*96 + c0;
        short* sp = samp + pl*872 + tap*96 + c0;
        #pragma unroll
        for (int m = 0; m < 3; m++) {
            float4 v00 = *(const float4*)(p00 + 4*m);
            float4 v01 = *(const float4*)(p01 + 4*m);
            float4 v10 = *(const float4*)(p10 + 4*m);
            float4 v11 = *(const float4*)(p11 + 4*m);
            float r0 = f00*v00.x + f01*v01.x + f10*v10.x + f11*v11.x;
            float r1 = f00*v00.y + f01*v01.y + f10*v10.y + f11*v11.y;
            float r2 = f00*v00.z + f01*v01.z + f10*v10.z + f11*v11.z;
            float r3 = f00*v00.w + f01*v01.w + f10*v10.w + f11*v11.w;
            s4v pk = { f2bs(r0), f2bs(r1), f2bs(r2), f2bs(r3) };
            *(s4v*)(sp + 4*m) = pk;
        }
    }
    __syncthreads();

    int l  = tid & 63;
    int wv = tid >> 6;
    int mt = wv >> 1;
    int ntb = (wv & 1) * 3;
    int q = l >> 4, mr = l & 15;

    const short* arow = samp + (16*mt + mr)*872 + q*8;
    ffrag acc0 = {0.f,0.f,0.f,0.f}, acc1 = acc0, acc2 = acc0;

    #pragma unroll 3
    for (int s = 0; s < 27; s++) {
        bfrag a  = *(const bfrag*)(arow + 32*s);
        const short* wb = wB + ((size_t)(s*6 + ntb)*64 + l)*8;
        bfrag b0 = *(const bfrag*)(wb);
        bfrag b1 = *(const bfrag*)(wb + 512);
        bfrag b2 = *(const bfrag*)(wb + 1024);
        acc0 = __builtin_amdgcn_mfma_f32_16x16x32_bf16(a, b0, acc0, 0, 0, 0);
        acc1 = __builtin_amdgcn_mfma_f32_16x16x32_bf16(a, b1, acc1, 0, 0, 0);
        acc2 = __builtin_amdgcn_mfma_f32_16x16x32_bf16(a, b2, acc2, 0, 0, 0);
    }

    ffrag accs[3] = {acc0, acc1, acc2};
    #pragma unroll
    for (int t = 0; t < 3; t++) {
        int o = 16*(ntb + t) + mr;
        float bo = bias[o];
        float* ob = out + ((size_t)b * OD + o) * HWD + hw0 + 16*mt + q*4;
        #pragma unroll
        for (int r = 0; r < 4; r++) ob[r] = accs[t][r] + bo;
    }
}

// ---------------------------------------------------------------------------
// Workspace layout (bytes):
//   x3      : 0          .. 25165824   (B*HW*96 fp32, NHWC)
//   offs    : 25165824   .. 29884416   (B*HW*18 fp32)
//   wB1     : 29884416   .. 30050304   (864*96 bf16, dconv B layout)
//   off_wT  : 30050304   .. 30112512
//   wB      : 30112512   .. 30278400   (864*96 bf16, def B layout)
// ---------------------------------------------------------------------------
extern "C" void kernel_launch(void* const* d_in, const int* in_sizes, int n_in,
                              void* d_out, int out_size, void* d_ws, size_t ws_size,
                              hipStream_t stream) {
    const float* x       = (const float*)d_in[0];
    const float* dconv_w = (const float*)d_in[1];
    const float* dconv_b = (const float*)d_in[2];
    const float* off_w   = (const float*)d_in[3];
    const float* off_b   = (const float*)d_in[4];
    const float* def_w   = (const float*)d_in[5];
    const float* def_b   = (const float*)d_in[6];
    float* out = (float*)d_out;

    char* ws = (char*)d_ws;
    float* x3     = (float*)(ws);
    float* offs   = (float*)(ws + 25165824);
    short* wB1    = (short*)(ws + 29884416);
    float* off_wT = (float*)(ws + 30050304);
    short* wB     = (short*)(ws + 30112512);

    k_repack<<<324, 256, 0, stream>>>(dconv_w, off_w, def_w, wB1, off_wT, wB);
    k_conv1<<<(BD*HWD)/32, 256, 0, stream>>>(x, wB1, dconv_b, x3);
    k_conv2<<<(BD*HWD)/256, 256, 0, stream>>>(x3, off_wT, off_b, offs);
    k_deform<<<(BD*HWD)/32, 256, 0, stream>>>(x3, offs, wB, def_b, out);
}

// Round 5
// 252.288 us; speedup vs baseline: 5.6066x; 1.2747x over previous
//
#include <hip/hip_runtime.h>
#include <hip/hip_bf16.h>

#define BD 4
#define CD 96
#define OD 96
#define HD 128
#define WD 128
#define HWD (HD*WD)          // 16384

#define COLS 36              // conv1 staged cols
#define CSTR 104             // shorts per (row,col): 96 + 8 pad

typedef __attribute__((ext_vector_type(8))) short bfrag;   // 8 bf16 (4 VGPRs)
typedef __attribute__((ext_vector_type(4))) float ffrag;   // 4 fp32 acc
typedef __attribute__((ext_vector_type(4))) short s4v;     // 4 bf16 (8 B)

__device__ __forceinline__ short f2bs(float f) {
    __hip_bfloat16 h = __float2bfloat16(f);
    return *reinterpret_cast<short*>(&h);
}

// ---------------------------------------------------------------------------
// Repack weights to bf16 MFMA B-frag layouts (k = tap*96 + c everywhere):
//   wB1 (864x96): dconv_w   wB2 (864x32, o<18 valid): off_w   wB (864x96): def_w
//   order: w[((s*NT+nt)*64 + l)*8 + j] = B[k=32s+(l>>4)*8+j][o=16nt+(l&15)]
// ---------------------------------------------------------------------------
__global__ void k_repack(const float* __restrict__ dconv_w,
                         const float* __restrict__ off_w,
                         const float* __restrict__ def_w,
                         short* __restrict__ wB1,
                         short* __restrict__ wB2,
                         short* __restrict__ wB) {
    int t = blockIdx.x * blockDim.x + threadIdx.x;
    if (t < 27648) {              // 864 x 32, NT=2
        int j = t & 7; int l = (t >> 3) & 63; int tile = t >> 9;
        int s = tile >> 1, nt = tile & 1;
        int k = 32*s + (l >> 4)*8 + j;
        int o = 16*nt + (l & 15);
        int c = k % 96, tap = k / 96;
        wB2[t] = (o < 18) ? f2bs(off_w[(o*96 + c)*9 + tap]) : (short)0;
    }
    if (t < 82944) {              // 864 x 96, NT=6
        int j = t & 7; int l = (t >> 3) & 63; int tile = t >> 9;
        int s = tile / 6, nt = tile % 6;
        int k = 32*s + (l >> 4)*8 + j;
        int o = 16*nt + (l & 15);
        int c = k % 96, tap = k / 96;
        wB1[t] = f2bs(dconv_w[(o*96 + c)*9 + tap]);
        wB[t]  = f2bs(def_w [(o*96 + c)*9 + tap]);
    }
}

// ---------------------------------------------------------------------------
// Kernel 1 (MFMA): x3 = x + relu(conv3x3 dil=2 pad=2 (x)) -> NHWC fp32
// (unchanged from R4)
// ---------------------------------------------------------------------------
__global__ __launch_bounds__(256) void k_conv1(const float* __restrict__ x,
                                               const short* __restrict__ wB,
                                               const float* __restrict__ bias,
                                               float* __restrict__ x3) {
    __shared__ short xt[3 * COLS * CSTR];   // 22464 B

    int pix0 = blockIdx.x * 32;
    int b = pix0 / HWD; int hw0 = pix0 % HWD;
    int h = hw0 / WD, w0 = hw0 % WD;
    int tid = threadIdx.x;
    const float* xb = x + (size_t)b * CD * HWD;

    for (int e = tid; e < 3*96*COLS; e += 256) {
        int col = e % COLS; int rc = e / COLS;
        int ro = rc / 96, c = rc % 96;
        int y  = h + ro*2 - 2;
        int xx = w0 - 2 + col;
        float v = ((unsigned)y < HD && (unsigned)xx < WD) ? xb[c*HWD + y*WD + xx] : 0.f;
        xt[(ro*COLS + col)*CSTR + c] = f2bs(v);
    }
    __syncthreads();

    int l  = tid & 63;
    int wv = tid >> 6;
    int mt = wv >> 1;
    int ntb = (wv & 1) * 3;
    int q = l >> 4, mr = l & 15;
    int px = 16*mt + mr;

    ffrag acc0 = {0.f,0.f,0.f,0.f}, acc1 = acc0, acc2 = acc0;

    #pragma unroll 3
    for (int s = 0; s < 27; s++) {
        int tap = s / 3;
        int ro  = tap / 3;
        int dxi = (tap % 3) * 2;
        int c0  = (s % 3) * 32 + q*8;
        bfrag a = *(const bfrag*)(xt + (ro*COLS + px + dxi)*CSTR + c0);
        const short* wb = wB + ((size_t)(s*6 + ntb)*64 + l)*8;
        bfrag b0 = *(const bfrag*)(wb);
        bfrag b1 = *(const bfrag*)(wb + 512);
        bfrag b2 = *(const bfrag*)(wb + 1024);
        acc0 = __builtin_amdgcn_mfma_f32_16x16x32_bf16(a, b0, acc0, 0, 0, 0);
        acc1 = __builtin_amdgcn_mfma_f32_16x16x32_bf16(a, b1, acc1, 0, 0, 0);
        acc2 = __builtin_amdgcn_mfma_f32_16x16x32_bf16(a, b2, acc2, 0, 0, 0);
    }

    ffrag accs[3] = {acc0, acc1, acc2};
    int hwb = hw0 + 16*mt + q*4;
    float* opb = x3 + ((size_t)b * HWD + hwb) * 96;
    #pragma unroll
    for (int t = 0; t < 3; t++) {
        int o = 16*(ntb + t) + mr;
        float bo = bias[o];
        float4 xr = *(const float4*)(xb + (size_t)o * HWD + hwb);
        float* op = opb + o;
        op[0]   = xr.x + fmaxf(accs[t][0] + bo, 0.f);
        op[96]  = xr.y + fmaxf(accs[t][1] + bo, 0.f);
        op[192] = xr.z + fmaxf(accs[t][2] + bo, 0.f);
        op[288] = xr.w + fmaxf(accs[t][3] + bo, 0.f);
    }
}

// ---------------------------------------------------------------------------
// Kernel 2 (fused): conv2 (offsets) + deformable sample + deform MFMA einsum.
// Block: 256 thr (4 waves), 32 row-consecutive pixels.
//  A1: stage x3 tile [3 rows][34 cols][96 ch] bf16 -> LDS (union w/ samp)
//  A2: offs[32][18] = MFMA conv over tile (taps = address offsets) -> offsb LDS
//  B : bilinear gather of x3 at offsets -> samp bf16 LDS
//  C : out[32][96] = samp[32][864] x wB[864][96] MFMA
// ---------------------------------------------------------------------------
__global__ __launch_bounds__(256) void k_deform(const float* __restrict__ x3,
                                                const short* __restrict__ wB2,
                                                const float* __restrict__ off_b,
                                                const short* __restrict__ wB,
                                                const float* __restrict__ bias,
                                                float* __restrict__ out) {
    __shared__ short buf[32 * 872];     // 55808 B: tile (A1/A2) then samp (B/C)
    __shared__ float offsb[32][20];     // 2560 B

    int pix0 = blockIdx.x * 32;
    int b = pix0 / HWD; int hw0 = pix0 % HWD;
    int h = hw0 / WD, w0 = hw0 % WD;
    int tid = threadIdx.x;
    const float* xb = x3 + (size_t)b * HWD * 96;

    // ---- Phase A1: stage x3 tile [3][34][96] (rows h-1..h+1, cols w0-1..w0+32)
    short* tile = buf;
    for (int e = tid; e < 3*34*96; e += 256) {
        int c = e % 96; int rc = e / 96;      // rc = ro*34 + col
        int ro = rc / 34, col = rc % 34;
        int y  = h + ro - 1;
        int xx = w0 - 1 + col;
        float v = ((unsigned)y < HD && (unsigned)xx < WD)
                    ? xb[((size_t)(y*WD + xx))*96 + c] : 0.f;
        tile[rc*CSTR + c] = f2bs(v);
    }
    __syncthreads();

    // ---- Phase A2: conv2 via MFMA -> offsb
    int l  = tid & 63;
    int wv = tid >> 6;
    int q = l >> 4, mr = l & 15;
    {
        int mt2 = wv & 1;           // px tile
        int nt2 = wv >> 1;          // o tile (0: o=0..15, 1: o=16..17)
        int px2 = 16*mt2 + mr;
        ffrag oacc = {0.f,0.f,0.f,0.f};
        #pragma unroll 3
        for (int s = 0; s < 27; s++) {
            int tap = s / 3;
            int ro  = tap / 3;
            int dxi = tap % 3;
            int c0  = (s % 3) * 32 + q*8;
            bfrag a  = *(const bfrag*)(tile + (ro*34 + px2 + dxi)*CSTR + c0);
            bfrag bb = *(const bfrag*)(wB2 + ((size_t)(s*2 + nt2)*64 + l)*8);
            oacc = __builtin_amdgcn_mfma_f32_16x16x32_bf16(a, bb, oacc, 0, 0, 0);
        }
        int o2 = 16*nt2 + mr;
        if (o2 < 18) {
            float bo = off_b[o2];
            #pragma unroll
            for (int r = 0; r < 4; r++)
                offsb[16*mt2 + q*4 + r][o2] = oacc[r] + bo;
        }
    }
    __syncthreads();

    // ---- Phase B: gather + bilinear lerp -> samp (overwrites tile)
    short* samp = buf;
    int pl = tid >> 3;          // pixel 0..31
    int ci = tid & 7;           // 12 channels each
    int hw = hw0 + pl;
    int w = w0 + pl;
    int c0 = ci * 12;

    #pragma unroll 1
    for (int tap = 0; tap < 9; tap++) {
        float dy = offsb[pl][tap*2], dx = offsb[pl][tap*2 + 1];
        float py  = (float)(h + tap/3 - 1) + dy;
        float pxf = (float)(w + tap%3 - 1) + dx;
        float y0f = floorf(py), x0f = floorf(pxf);
        float wy = py - y0f, wx = pxf - x0f;
        int y0 = (int)y0f, x0 = (int)x0f;
        int y1 = y0 + 1, x1 = x0 + 1;
        bool vy0 = (unsigned)y0 < HD, vy1 = (unsigned)y1 < HD;
        bool vx0 = (unsigned)x0 < WD, vx1 = (unsigned)x1 < WD;
        float f00 = (vy0 && vx0) ? (1.f-wy)*(1.f-wx) : 0.f;
        float f01 = (vy0 && vx1) ? (1.f-wy)*wx       : 0.f;
        float f10 = (vy1 && vx0) ? wy*(1.f-wx)       : 0.f;
        float f11 = (vy1 && vx1) ? wy*wx             : 0.f;
        int yc0 = min(max(y0,0),HD-1), yc1 = min(max(y1,0),HD-1);
        int xc0 = min(max(x0,0),WD-1), xc1 = min(max(x1,0),WD-1);
        const float* p00 = xb + (yc0*WD + xc0)*96 + c0;
        const float* p01 = xb + (yc0*WD + xc1)*96 + c0;
        const float* p10 = xb + (yc1*WD + xc0)*96 + c0;
        const float* p11 = xb + (yc1*WD + xc1)*96 + c0;
        short* sp = samp + pl*872 + tap*96 + c0;
        #pragma unroll
        for (int m = 0; m < 3; m++) {
            float4 v00 = *(const float4*)(p00 + 4*m);
            float4 v01 = *(const float4*)(p01 + 4*m);
            float4 v10 = *(const float4*)(p10 + 4*m);
            float4 v11 = *(const float4*)(p11 + 4*m);
            float r0 = f00*v00.x + f01*v01.x + f10*v10.x + f11*v11.x;
            float r1 = f00*v00.y + f01*v01.y + f10*v10.y + f11*v11.y;
            float r2 = f00*v00.z + f01*v01.z + f10*v10.z + f11*v11.z;
            float r3 = f00*v00.w + f01*v01.w + f10*v10.w + f11*v11.w;
            s4v pk = { f2bs(r0), f2bs(r1), f2bs(r2), f2bs(r3) };
            *(s4v*)(sp + 4*m) = pk;
        }
    }
    __syncthreads();

    // ---- Phase C: deform MFMA GEMM
    int mt = wv >> 1;
    int ntb = (wv & 1) * 3;

    const short* arow = samp + (16*mt + mr)*872 + q*8;
    ffrag acc0 = {0.f,0.f,0.f,0.f}, acc1 = acc0, acc2 = acc0;

    #pragma unroll 3
    for (int s = 0; s < 27; s++) {
        bfrag a  = *(const bfrag*)(arow + 32*s);
        const short* wb = wB + ((size_t)(s*6 + ntb)*64 + l)*8;
        bfrag b0 = *(const bfrag*)(wb);
        bfrag b1 = *(const bfrag*)(wb + 512);
        bfrag b2 = *(const bfrag*)(wb + 1024);
        acc0 = __builtin_amdgcn_mfma_f32_16x16x32_bf16(a, b0, acc0, 0, 0, 0);
        acc1 = __builtin_amdgcn_mfma_f32_16x16x32_bf16(a, b1, acc1, 0, 0, 0);
        acc2 = __builtin_amdgcn_mfma_f32_16x16x32_bf16(a, b2, acc2, 0, 0, 0);
    }

    ffrag accs[3] = {acc0, acc1, acc2};
    #pragma unroll
    for (int t = 0; t < 3; t++) {
        int o = 16*(ntb + t) + mr;
        float bo = bias[o];
        float* ob = out + ((size_t)b * OD + o) * HWD + hw0 + 16*mt + q*4;
        #pragma unroll
        for (int r = 0; r < 4; r++) ob[r] = accs[t][r] + bo;
    }
}

// ---------------------------------------------------------------------------
// Workspace layout (bytes):
//   x3  : 0        .. 25165824   (B*HW*96 fp32, NHWC)
//   wB1 : 25165824 .. 25331712   (864*96 bf16, dconv B layout)
//   wB2 : 25331712 .. 25387008   (864*32 bf16, off_w B layout)
//   wB  : 25387008 .. 25552896   (864*96 bf16, def_w B layout)
// ---------------------------------------------------------------------------
extern "C" void kernel_launch(void* const* d_in, const int* in_sizes, int n_in,
                              void* d_out, int out_size, void* d_ws, size_t ws_size,
                              hipStream_t stream) {
    const float* x       = (const float*)d_in[0];
    const float* dconv_w = (const float*)d_in[1];
    const float* dconv_b = (const float*)d_in[2];
    const float* off_w   = (const float*)d_in[3];
    const float* off_b   = (const float*)d_in[4];
    const float* def_w   = (const float*)d_in[5];
    const float* def_b   = (const float*)d_in[6];
    float* out = (float*)d_out;

    char* ws = (char*)d_ws;
    float* x3  = (float*)(ws);
    short* wB1 = (short*)(ws + 25165824);
    short* wB2 = (short*)(ws + 25331712);
    short* wB  = (short*)(ws + 25387008);

    k_repack<<<324, 256, 0, stream>>>(dconv_w, off_w, def_w, wB1, wB2, wB);
    k_conv1<<<(BD*HWD)/32, 256, 0, stream>>>(x, wB1, dconv_b, x3);
    k_deform<<<(BD*HWD)/32, 256, 0, stream>>>(x3, wB2, off_b, wB, def_b, out);
}

// Round 6
// 206.879 us; speedup vs baseline: 6.8372x; 1.2195x over previous
//
#include <hip/hip_runtime.h>
#include <hip/hip_bf16.h>

#define BD 4
#define CD 96
#define OD 96
#define HD 128
#define WD 128
#define HWD (HD*WD)          // 16384

typedef __attribute__((ext_vector_type(8))) short bfrag;   // 8 bf16 (4 VGPRs)
typedef __attribute__((ext_vector_type(4))) float ffrag;   // 4 fp32 acc

__device__ __forceinline__ short f2bs(float f) {
    __hip_bfloat16 h = __float2bfloat16(f);
    return *reinterpret_cast<short*>(&h);
}

// ---------------------------------------------------------------------------
// Transpose: x (NCHW fp32) -> xb16 (pixel-major NHWC bf16)
// Block: 256 thr, 256 pixels. LDS tile 256x104 shorts.
// ---------------------------------------------------------------------------
__global__ __launch_bounds__(256) void k_transpose(const float* __restrict__ x,
                                                   short* __restrict__ xb16) {
    __shared__ short tile[256 * 104];
    int pix0 = blockIdx.x * 256;
    int b = pix0 / HWD; int hw0 = pix0 % HWD;
    int tid = threadIdx.x;

    for (int e = tid; e < 96*64; e += 256) {
        int c = e >> 6, g = e & 63;
        float4 v = *(const float4*)(x + ((size_t)(b*96 + c))*HWD + hw0 + 4*g);
        tile[(4*g+0)*104 + c] = f2bs(v.x);
        tile[(4*g+1)*104 + c] = f2bs(v.y);
        tile[(4*g+2)*104 + c] = f2bs(v.z);
        tile[(4*g+3)*104 + c] = f2bs(v.w);
    }
    __syncthreads();
    for (int e = tid; e < 256*12; e += 256) {
        int px = e / 12, c8 = e % 12;
        bfrag v = *(const bfrag*)(tile + px*104 + c8*8);
        *(bfrag*)(xb16 + ((size_t)(pix0 + px))*96 + c8*8) = v;
    }
}

// ---------------------------------------------------------------------------
// Repack weights to bf16 MFMA B-frag layouts (k = tap*96 + c):
//   wB1 (864x96): dconv_w   wB2 (864x32, o<18): off_w   wB (864x96): def_w
//   order: w[((s*NT+nt)*64 + l)*8 + j] = B[k=32s+(l>>4)*8+j][o=16nt+(l&15)]
// ---------------------------------------------------------------------------
__global__ void k_repack(const float* __restrict__ dconv_w,
                         const float* __restrict__ off_w,
                         const float* __restrict__ def_w,
                         short* __restrict__ wB1,
                         short* __restrict__ wB2,
                         short* __restrict__ wB) {
    int t = blockIdx.x * blockDim.x + threadIdx.x;
    if (t < 27648) {              // 864 x 32, NT=2
        int j = t & 7; int l = (t >> 3) & 63; int tile = t >> 9;
        int s = tile >> 1, nt = tile & 1;
        int k = 32*s + (l >> 4)*8 + j;
        int o = 16*nt + (l & 15);
        int c = k % 96, tap = k / 96;
        wB2[t] = (o < 18) ? f2bs(off_w[(o*96 + c)*9 + tap]) : (short)0;
    }
    if (t < 82944) {              // 864 x 96, NT=6
        int j = t & 7; int l = (t >> 3) & 63; int tile = t >> 9;
        int s = tile / 6, nt = tile % 6;
        int k = 32*s + (l >> 4)*8 + j;
        int o = 16*nt + (l & 15);
        int c = k % 96, tap = k / 96;
        wB1[t] = f2bs(dconv_w[(o*96 + c)*9 + tap]);
        wB[t]  = f2bs(def_w [(o*96 + c)*9 + tap]);
    }
}

// ---------------------------------------------------------------------------
// Kernel 1 (LDS-free MFMA): x3b = bf16(x + relu(conv3x3 dil2 pad2(x))), NHWC
// Block: 256 thr = 4 independent waves; wave owns 16 pixels, all 96 outputs.
// A-frags direct from global xb16; taps = address shifts (y uniform-skip,
// x per-lane mask).
// ---------------------------------------------------------------------------
__global__ __launch_bounds__(256, 3) void k_conv1(const float* __restrict__ x,
                                                  const short* __restrict__ xb16,
                                                  const short* __restrict__ wB,
                                                  const float* __restrict__ bias,
                                                  short* __restrict__ x3b) {
    int pix0 = blockIdx.x * 64;
    int b = pix0 / HWD; int hw0 = pix0 % HWD;
    int h = hw0 / WD, w0 = hw0 % WD;
    int tid = threadIdx.x;
    int l = tid & 63, wv = tid >> 6;
    int q = l >> 4, mr = l & 15;
    int wq = w0 + 16*wv;                 // wave's first pixel col
    const short* xb = xb16 + ((size_t)b * HWD) * 96;
    const bfrag az = {0,0,0,0,0,0,0,0};

    ffrag acc[6];
    #pragma unroll
    for (int nt = 0; nt < 6; nt++) acc[nt] = ffrag{0.f,0.f,0.f,0.f};

    #pragma unroll 1
    for (int tap = 0; tap < 9; tap++) {
        int y = h + (tap/3)*2 - 2;
        if ((unsigned)y >= HD) continue;
        int xx = wq + mr + (tap%3)*2 - 2;
        int xxc = min(max(xx, 0), WD-1);
        bool vx = (unsigned)xx < WD;
        const short* abase = xb + ((size_t)(y*WD + xxc))*96 + q*8;
        #pragma unroll
        for (int sc = 0; sc < 3; sc++) {
            int s = tap*3 + sc;
            bfrag a = *(const bfrag*)(abase + sc*32);
            if (!vx) a = az;
            const short* wb = wB + ((size_t)(s*6)*64 + l)*8;
            #pragma unroll
            for (int nt = 0; nt < 6; nt++) {
                bfrag bb = *(const bfrag*)(wb + nt*512);
                acc[nt] = __builtin_amdgcn_mfma_f32_16x16x32_bf16(a, bb, acc[nt], 0, 0, 0);
            }
        }
    }

    // epilogue: lane holds D[m=q*4+r][o=16nt+mr]; residual from x (NCHW fp32)
    int hwb = hw0 + 16*wv + q*4;
    #pragma unroll
    for (int nt = 0; nt < 6; nt++) {
        int o = 16*nt + mr;
        float bo = bias[o];
        float4 xr = *(const float4*)(x + ((size_t)(b*96 + o))*HWD + hwb);
        short* op = x3b + ((size_t)(b*HWD + hwb))*96 + o;
        op[0]   = f2bs(xr.x + fmaxf(acc[nt][0] + bo, 0.f));
        op[96]  = f2bs(xr.y + fmaxf(acc[nt][1] + bo, 0.f));
        op[192] = f2bs(xr.z + fmaxf(acc[nt][2] + bo, 0.f));
        op[288] = f2bs(xr.w + fmaxf(acc[nt][3] + bo, 0.f));
    }
}

// ---------------------------------------------------------------------------
// Kernel 2 (fused, wave-autonomous): conv2-MFMA -> offsets (5KB LDS, no
// barriers) -> bilinear gather (registers) -> deform MFMA -> out.
// Block: 256 thr = 4 independent waves; wave owns 16 pixels.
// ---------------------------------------------------------------------------
__global__ __launch_bounds__(256, 3) void k_deform(const short* __restrict__ x3b,
                                                   const short* __restrict__ wB2,
                                                   const float* __restrict__ off_b,
                                                   const short* __restrict__ wB,
                                                   const float* __restrict__ def_b,
                                                   float* __restrict__ out) {
    __shared__ float offsb[64][20];

    int pix0 = blockIdx.x * 64;
    int b = pix0 / HWD; int hw0 = pix0 % HWD;
    int h = hw0 / WD, w0 = hw0 % WD;
    int tid = threadIdx.x;
    int l = tid & 63, wv = tid >> 6;
    int q = l >> 4, mr = l & 15;
    int wq = w0 + 16*wv;
    const short* xb = x3b + ((size_t)b * HWD) * 96;
    const bfrag az = {0,0,0,0,0,0,0,0};

    // ---- conv2 via MFMA: offsets for this wave's 16 pixels ----
    ffrag oa0 = {0.f,0.f,0.f,0.f}, oa1 = oa0;
    #pragma unroll 1
    for (int tap = 0; tap < 9; tap++) {
        int y = h + tap/3 - 1;
        if ((unsigned)y >= HD) continue;
        int xx = wq + mr + tap%3 - 1;
        int xxc = min(max(xx, 0), WD-1);
        bool vx = (unsigned)xx < WD;
        const short* abase = xb + ((size_t)(y*WD + xxc))*96 + q*8;
        #pragma unroll
        for (int sc = 0; sc < 3; sc++) {
            int s = tap*3 + sc;
            bfrag a = *(const bfrag*)(abase + sc*32);
            if (!vx) a = az;
            const short* wb = wB2 + ((size_t)(s*2)*64 + l)*8;
            bfrag b0 = *(const bfrag*)(wb);
            bfrag b1 = *(const bfrag*)(wb + 512);
            oa0 = __builtin_amdgcn_mfma_f32_16x16x32_bf16(a, b0, oa0, 0, 0, 0);
            oa1 = __builtin_amdgcn_mfma_f32_16x16x32_bf16(a, b1, oa1, 0, 0, 0);
        }
    }
    {
        int row = 16*wv + q*4;
        float bo0 = off_b[mr];
        #pragma unroll
        for (int r = 0; r < 4; r++) offsb[row + r][mr] = oa0[r] + bo0;
        if (mr < 2) {
            float bo1 = off_b[16 + mr];
            #pragma unroll
            for (int r = 0; r < 4; r++) offsb[row + r][16 + mr] = oa1[r] + bo1;
        }
    }
    // no __syncthreads: offsb rows 16wv..16wv+15 produced & consumed by wave wv

    // ---- gather + deform MFMA ----
    int w = wq + mr;                    // lane's pixel col (A-row m = mr)
    ffrag acc[6];
    #pragma unroll
    for (int nt = 0; nt < 6; nt++) acc[nt] = ffrag{0.f,0.f,0.f,0.f};

    #pragma unroll 1
    for (int tap = 0; tap < 9; tap++) {
        float dy = offsb[16*wv + mr][2*tap];
        float dx = offsb[16*wv + mr][2*tap + 1];
        float py  = (float)(h + tap/3 - 1) + dy;
        float pxf = (float)(w + tap%3 - 1) + dx;
        float y0f = floorf(py), x0f = floorf(pxf);
        float wy = py - y0f, wx = pxf - x0f;
        int y0 = (int)y0f, x0 = (int)x0f;
        int y1 = y0 + 1, x1 = x0 + 1;
        bool vy0 = (unsigned)y0 < HD, vy1 = (unsigned)y1 < HD;
        bool vx0 = (unsigned)x0 < WD, vx1 = (unsigned)x1 < WD;
        float f00 = (vy0 && vx0) ? (1.f-wy)*(1.f-wx) : 0.f;
        float f01 = (vy0 && vx1) ? (1.f-wy)*wx       : 0.f;
        float f10 = (vy1 && vx0) ? wy*(1.f-wx)       : 0.f;
        float f11 = (vy1 && vx1) ? wy*wx             : 0.f;
        int yc0 = min(max(y0,0),HD-1), yc1 = min(max(y1,0),HD-1);
        int xc0 = min(max(x0,0),WD-1), xc1 = min(max(x1,0),WD-1);
        const short* p00 = xb + ((size_t)(yc0*WD + xc0))*96 + q*8;
        const short* p01 = xb + ((size_t)(yc0*WD + xc1))*96 + q*8;
        const short* p10 = xb + ((size_t)(yc1*WD + xc0))*96 + q*8;
        const short* p11 = xb + ((size_t)(yc1*WD + xc1))*96 + q*8;
        #pragma unroll
        for (int sc = 0; sc < 3; sc++) {
            bfrag c00 = *(const bfrag*)(p00 + sc*32);
            bfrag c01 = *(const bfrag*)(p01 + sc*32);
            bfrag c10 = *(const bfrag*)(p10 + sc*32);
            bfrag c11 = *(const bfrag*)(p11 + sc*32);
            const int* i00 = (const int*)&c00;
            const int* i01 = (const int*)&c01;
            const int* i10 = (const int*)&c10;
            const int* i11 = (const int*)&c11;
            int ap[4];
            #pragma unroll
            for (int d = 0; d < 4; d++) {
                float a0 = __int_as_float(((unsigned)i00[d]) << 16);
                float b0f = __int_as_float(((unsigned)i01[d]) << 16);
                float c0f = __int_as_float(((unsigned)i10[d]) << 16);
                float d0 = __int_as_float(((unsigned)i11[d]) << 16);
                float a1 = __int_as_float(i00[d] & 0xffff0000);
                float b1f = __int_as_float(i01[d] & 0xffff0000);
                float c1f = __int_as_float(i10[d] & 0xffff0000);
                float d1 = __int_as_float(i11[d] & 0xffff0000);
                float rlo = f00*a0 + f01*b0f + f10*c0f + f11*d0;
                float rhi = f00*a1 + f01*b1f + f10*c1f + f11*d1;
                ap[d] = (int)((unsigned short)f2bs(rlo)) |
                        ((int)((unsigned short)f2bs(rhi)) << 16);
            }
            bfrag a = *(const bfrag*)ap;
            int s = tap*3 + sc;
            const short* wb = wB + ((size_t)(s*6)*64 + l)*8;
            #pragma unroll
            for (int nt = 0; nt < 6; nt++) {
                bfrag bb = *(const bfrag*)(wb + nt*512);
                acc[nt] = __builtin_amdgcn_mfma_f32_16x16x32_bf16(a, bb, acc[nt], 0, 0, 0);
            }
        }
    }

    // ---- epilogue: NCHW fp32 out, float4 per n-tile ----
    int hwb = hw0 + 16*wv + q*4;
    #pragma unroll
    for (int nt = 0; nt < 6; nt++) {
        int o = 16*nt + mr;
        float bo = def_b[o];
        float4 v;
        v.x = acc[nt][0] + bo; v.y = acc[nt][1] + bo;
        v.z = acc[nt][2] + bo; v.w = acc[nt][3] + bo;
        *(float4*)(out + ((size_t)(b*96 + o))*HWD + hwb) = v;
    }
}

// ---------------------------------------------------------------------------
// Workspace layout (bytes):
//   xb16 : 0        .. 12582912   (B*HW*96 bf16, NHWC of x)
//   x3b  : 12582912 .. 25165824   (B*HW*96 bf16, NHWC of x3)
//   wB1  : 25165824 .. 25331712
//   wB2  : 25331712 .. 25387008
//   wB   : 25387008 .. 25552896
// ---------------------------------------------------------------------------
extern "C" void kernel_launch(void* const* d_in, const int* in_sizes, int n_in,
                              void* d_out, int out_size, void* d_ws, size_t ws_size,
                              hipStream_t stream) {
    const float* x       = (const float*)d_in[0];
    const float* dconv_w = (const float*)d_in[1];
    const float* dconv_b = (const float*)d_in[2];
    const float* off_w   = (const float*)d_in[3];
    const float* off_b   = (const float*)d_in[4];
    const float* def_w   = (const float*)d_in[5];
    const float* def_b   = (const float*)d_in[6];
    float* out = (float*)d_out;

    char* ws = (char*)d_ws;
    short* xb16 = (short*)(ws);
    short* x3b  = (short*)(ws + 12582912);
    short* wB1  = (short*)(ws + 25165824);
    short* wB2  = (short*)(ws + 25331712);
    short* wB   = (short*)(ws + 25387008);

    k_repack<<<324, 256, 0, stream>>>(dconv_w, off_w, def_w, wB1, wB2, wB);
    k_transpose<<<(BD*HWD)/256, 256, 0, stream>>>(x, xb16);
    k_conv1<<<(BD*HWD)/64, 256, 0, stream>>>(x, xb16, wB1, dconv_b, x3b);
    k_deform<<<(BD*HWD)/64, 256, 0, stream>>>(x3b, wB2, off_b, wB, def_b, out);
}

// Round 7
// 196.822 us; speedup vs baseline: 7.1865x; 1.0511x over previous
//
#include <hip/hip_runtime.h>
#include <hip/hip_bf16.h>

#define BD 4
#define CD 96
#define OD 96
#define HD 128
#define WD 128
#define HWD (HD*WD)          // 16384

typedef __attribute__((ext_vector_type(8))) short bfrag;   // 8 bf16 (4 VGPRs)
typedef __attribute__((ext_vector_type(4))) float ffrag;   // 4 fp32 acc

__device__ __forceinline__ short f2bs(float f) {
    __hip_bfloat16 h = __float2bfloat16(f);
    return *reinterpret_cast<short*>(&h);
}

// XCD-aware swizzle for 1024-block launches: dispatch is round-robin over 8
// XCDs (blockIdx % 8). Give XCD k a contiguous 128-logical-block band (64
// image rows) so gather/tap halos stay in that XCD's 4 MiB L2.
__device__ __forceinline__ int swizzle1024(int gid) {
    return ((gid & 7) << 7) | (gid >> 3);
}

// ---------------------------------------------------------------------------
// Transpose: x (NCHW fp32) -> xb16 (pixel-major NHWC bf16)
// ---------------------------------------------------------------------------
__global__ __launch_bounds__(256) void k_transpose(const float* __restrict__ x,
                                                   short* __restrict__ xb16) {
    __shared__ short tile[256 * 104];
    int pix0 = blockIdx.x * 256;
    int b = pix0 / HWD; int hw0 = pix0 % HWD;
    int tid = threadIdx.x;

    for (int e = tid; e < 96*64; e += 256) {
        int c = e >> 6, g = e & 63;
        float4 v = *(const float4*)(x + ((size_t)(b*96 + c))*HWD + hw0 + 4*g);
        tile[(4*g+0)*104 + c] = f2bs(v.x);
        tile[(4*g+1)*104 + c] = f2bs(v.y);
        tile[(4*g+2)*104 + c] = f2bs(v.z);
        tile[(4*g+3)*104 + c] = f2bs(v.w);
    }
    __syncthreads();
    for (int e = tid; e < 256*12; e += 256) {
        int px = e / 12, c8 = e % 12;
        bfrag v = *(const bfrag*)(tile + px*104 + c8*8);
        *(bfrag*)(xb16 + ((size_t)(pix0 + px))*96 + c8*8) = v;
    }
}

// ---------------------------------------------------------------------------
// Repack weights to bf16 MFMA B-frag layouts (k = tap*96 + c):
//   wB1 (864x96): dconv_w   wB2 (864x32, o<18): off_w   wB (864x96): def_w
//   order: w[((s*NT+nt)*64 + l)*8 + j] = B[k=32s+(l>>4)*8+j][o=16nt+(l&15)]
// ---------------------------------------------------------------------------
__global__ void k_repack(const float* __restrict__ dconv_w,
                         const float* __restrict__ off_w,
                         const float* __restrict__ def_w,
                         short* __restrict__ wB1,
                         short* __restrict__ wB2,
                         short* __restrict__ wB) {
    int t = blockIdx.x * blockDim.x + threadIdx.x;
    if (t < 27648) {              // 864 x 32, NT=2
        int j = t & 7; int l = (t >> 3) & 63; int tile = t >> 9;
        int s = tile >> 1, nt = tile & 1;
        int k = 32*s + (l >> 4)*8 + j;
        int o = 16*nt + (l & 15);
        int c = k % 96, tap = k / 96;
        wB2[t] = (o < 18) ? f2bs(off_w[(o*96 + c)*9 + tap]) : (short)0;
    }
    if (t < 82944) {              // 864 x 96, NT=6
        int j = t & 7; int l = (t >> 3) & 63; int tile = t >> 9;
        int s = tile / 6, nt = tile % 6;
        int k = 32*s + (l >> 4)*8 + j;
        int o = 16*nt + (l & 15);
        int c = k % 96, tap = k / 96;
        wB1[t] = f2bs(dconv_w[(o*96 + c)*9 + tap]);
        wB[t]  = f2bs(def_w [(o*96 + c)*9 + tap]);
    }
}

// ---------------------------------------------------------------------------
// Kernel 1 (LDS-free MFMA): x3b = bf16(x + relu(conv3x3 dil2 pad2(x))), NHWC
// ---------------------------------------------------------------------------
__global__ __launch_bounds__(256, 3) void k_conv1(const float* __restrict__ x,
                                                  const short* __restrict__ xb16,
                                                  const short* __restrict__ wB,
                                                  const float* __restrict__ bias,
                                                  short* __restrict__ x3b) {
    int pix0 = swizzle1024(blockIdx.x) * 64;
    int b = pix0 / HWD; int hw0 = pix0 % HWD;
    int h = hw0 / WD, w0 = hw0 % WD;
    int tid = threadIdx.x;
    int l = tid & 63, wv = tid >> 6;
    int q = l >> 4, mr = l & 15;
    int wq = w0 + 16*wv;                 // wave's first pixel col
    const short* xb = xb16 + ((size_t)b * HWD) * 96;
    const bfrag az = {0,0,0,0,0,0,0,0};

    ffrag acc[6];
    #pragma unroll
    for (int nt = 0; nt < 6; nt++) acc[nt] = ffrag{0.f,0.f,0.f,0.f};

    #pragma unroll 1
    for (int tap = 0; tap < 9; tap++) {
        int y = h + (tap/3)*2 - 2;
        if ((unsigned)y >= HD) continue;
        int xx = wq + mr + (tap%3)*2 - 2;
        int xxc = min(max(xx, 0), WD-1);
        bool vx = (unsigned)xx < WD;
        const short* abase = xb + ((size_t)(y*WD + xxc))*96 + q*8;
        #pragma unroll
        for (int sc = 0; sc < 3; sc++) {
            int s = tap*3 + sc;
            bfrag a = *(const bfrag*)(abase + sc*32);
            if (!vx) a = az;
            const short* wb = wB + ((size_t)(s*6)*64 + l)*8;
            #pragma unroll
            for (int nt = 0; nt < 6; nt++) {
                bfrag bb = *(const bfrag*)(wb + nt*512);
                acc[nt] = __builtin_amdgcn_mfma_f32_16x16x32_bf16(a, bb, acc[nt], 0, 0, 0);
            }
        }
    }

    int hwb = hw0 + 16*wv + q*4;
    #pragma unroll
    for (int nt = 0; nt < 6; nt++) {
        int o = 16*nt + mr;
        float bo = bias[o];
        float4 xr = *(const float4*)(x + ((size_t)(b*96 + o))*HWD + hwb);
        short* op = x3b + ((size_t)(b*HWD + hwb))*96 + o;
        op[0]   = f2bs(xr.x + fmaxf(acc[nt][0] + bo, 0.f));
        op[96]  = f2bs(xr.y + fmaxf(acc[nt][1] + bo, 0.f));
        op[192] = f2bs(xr.z + fmaxf(acc[nt][2] + bo, 0.f));
        op[288] = f2bs(xr.w + fmaxf(acc[nt][3] + bo, 0.f));
    }
}

// ---------------------------------------------------------------------------
// Kernel 2 (fused, wave-autonomous): conv2-MFMA -> offsets (5KB LDS, no
// barriers) -> bilinear gather (registers) -> deform MFMA -> out.
// ---------------------------------------------------------------------------
__global__ __launch_bounds__(256, 3) void k_deform(const short* __restrict__ x3b,
                                                   const short* __restrict__ wB2,
                                                   const float* __restrict__ off_b,
                                                   const short* __restrict__ wB,
                                                   const float* __restrict__ def_b,
                                                   float* __restrict__ out) {
    __shared__ float offsb[64][20];

    int pix0 = swizzle1024(blockIdx.x) * 64;
    int b = pix0 / HWD; int hw0 = pix0 % HWD;
    int h = hw0 / WD, w0 = hw0 % WD;
    int tid = threadIdx.x;
    int l = tid & 63, wv = tid >> 6;
    int q = l >> 4, mr = l & 15;
    int wq = w0 + 16*wv;
    const short* xb = x3b + ((size_t)b * HWD) * 96;
    const bfrag az = {0,0,0,0,0,0,0,0};

    // ---- conv2 via MFMA: offsets for this wave's 16 pixels ----
    ffrag oa0 = {0.f,0.f,0.f,0.f}, oa1 = oa0;
    #pragma unroll 1
    for (int tap = 0; tap < 9; tap++) {
        int y = h + tap/3 - 1;
        if ((unsigned)y >= HD) continue;
        int xx = wq + mr + tap%3 - 1;
        int xxc = min(max(xx, 0), WD-1);
        bool vx = (unsigned)xx < WD;
        const short* abase = xb + ((size_t)(y*WD + xxc))*96 + q*8;
        #pragma unroll
        for (int sc = 0; sc < 3; sc++) {
            int s = tap*3 + sc;
            bfrag a = *(const bfrag*)(abase + sc*32);
            if (!vx) a = az;
            const short* wb = wB2 + ((size_t)(s*2)*64 + l)*8;
            bfrag b0 = *(const bfrag*)(wb);
            bfrag b1 = *(const bfrag*)(wb + 512);
            oa0 = __builtin_amdgcn_mfma_f32_16x16x32_bf16(a, b0, oa0, 0, 0, 0);
            oa1 = __builtin_amdgcn_mfma_f32_16x16x32_bf16(a, b1, oa1, 0, 0, 0);
        }
    }
    {
        int row = 16*wv + q*4;
        float bo0 = off_b[mr];
        #pragma unroll
        for (int r = 0; r < 4; r++) offsb[row + r][mr] = oa0[r] + bo0;
        if (mr < 2) {
            float bo1 = off_b[16 + mr];
            #pragma unroll
            for (int r = 0; r < 4; r++) offsb[row + r][16 + mr] = oa1[r] + bo1;
        }
    }
    // no __syncthreads: offsb rows 16wv..16wv+15 produced & consumed by wave wv

    // ---- gather + deform MFMA ----
    int w = wq + mr;
    ffrag acc[6];
    #pragma unroll
    for (int nt = 0; nt < 6; nt++) acc[nt] = ffrag{0.f,0.f,0.f,0.f};

    #pragma unroll 1
    for (int tap = 0; tap < 9; tap++) {
        float dy = offsb[16*wv + mr][2*tap];
        float dx = offsb[16*wv + mr][2*tap + 1];
        float py  = (float)(h + tap/3 - 1) + dy;
        float pxf = (float)(w + tap%3 - 1) + dx;
        float y0f = floorf(py), x0f = floorf(pxf);
        float wy = py - y0f, wx = pxf - x0f;
        int y0 = (int)y0f, x0 = (int)x0f;
        int y1 = y0 + 1, x1 = x0 + 1;
        bool vy0 = (unsigned)y0 < HD, vy1 = (unsigned)y1 < HD;
        bool vx0 = (unsigned)x0 < WD, vx1 = (unsigned)x1 < WD;
        float f00 = (vy0 && vx0) ? (1.f-wy)*(1.f-wx) : 0.f;
        float f01 = (vy0 && vx1) ? (1.f-wy)*wx       : 0.f;
        float f10 = (vy1 && vx0) ? wy*(1.f-wx)       : 0.f;
        float f11 = (vy1 && vx1) ? wy*wx             : 0.f;
        int yc0 = min(max(y0,0),HD-1), yc1 = min(max(y1,0),HD-1);
        int xc0 = min(max(x0,0),WD-1), xc1 = min(max(x1,0),WD-1);
        const short* p00 = xb + ((size_t)(yc0*WD + xc0))*96 + q*8;
        const short* p01 = xb + ((size_t)(yc0*WD + xc1))*96 + q*8;
        const short* p10 = xb + ((size_t)(yc1*WD + xc0))*96 + q*8;
        const short* p11 = xb + ((size_t)(yc1*WD + xc1))*96 + q*8;
        #pragma unroll
        for (int sc = 0; sc < 3; sc++) {
            bfrag c00 = *(const bfrag*)(p00 + sc*32);
            bfrag c01 = *(const bfrag*)(p01 + sc*32);
            bfrag c10 = *(const bfrag*)(p10 + sc*32);
            bfrag c11 = *(const bfrag*)(p11 + sc*32);
            const int* i00 = (const int*)&c00;
            const int* i01 = (const int*)&c01;
            const int* i10 = (const int*)&c10;
            const int* i11 = (const int*)&c11;
            int ap[4];
            #pragma unroll
            for (int d = 0; d < 4; d++) {
                float a0 = __int_as_float(((unsigned)i00[d]) << 16);
                float b0f = __int_as_float(((unsigned)i01[d]) << 16);
                float c0f = __int_as_float(((unsigned)i10[d]) << 16);
                float d0 = __int_as_float(((unsigned)i11[d]) << 16);
                float a1 = __int_as_float(i00[d] & 0xffff0000);
                float b1f = __int_as_float(i01[d] & 0xffff0000);
                float c1f = __int_as_float(i10[d] & 0xffff0000);
                float d1 = __int_as_float(i11[d] & 0xffff0000);
                float rlo = f00*a0 + f01*b0f + f10*c0f + f11*d0;
                float rhi = f00*a1 + f01*b1f + f10*c1f + f11*d1;
                ap[d] = (int)((unsigned short)f2bs(rlo)) |
                        ((int)((unsigned short)f2bs(rhi)) << 16);
            }
            bfrag a = *(const bfrag*)ap;
            int s = tap*3 + sc;
            const short* wb = wB + ((size_t)(s*6)*64 + l)*8;
            #pragma unroll
            for (int nt = 0; nt < 6; nt++) {
                bfrag bb = *(const bfrag*)(wb + nt*512);
                acc[nt] = __builtin_amdgcn_mfma_f32_16x16x32_bf16(a, bb, acc[nt], 0, 0, 0);
            }
        }
    }

    // ---- epilogue: NCHW fp32 out, float4 per n-tile ----
    int hwb = hw0 + 16*wv + q*4;
    #pragma unroll
    for (int nt = 0; nt < 6; nt++) {
        int o = 16*nt + mr;
        float bo = def_b[o];
        float4 v;
        v.x = acc[nt][0] + bo; v.y = acc[nt][1] + bo;
        v.z = acc[nt][2] + bo; v.w = acc[nt][3] + bo;
        *(float4*)(out + ((size_t)(b*96 + o))*HWD + hwb) = v;
    }
}

// ---------------------------------------------------------------------------
// Workspace layout (bytes):
//   xb16 : 0        .. 12582912   (B*HW*96 bf16, NHWC of x)
//   x3b  : 12582912 .. 25165824   (B*HW*96 bf16, NHWC of x3)
//   wB1  : 25165824 .. 25331712
//   wB2  : 25331712 .. 25387008
//   wB   : 25387008 .. 25552896
// ---------------------------------------------------------------------------
extern "C" void kernel_launch(void* const* d_in, const int* in_sizes, int n_in,
                              void* d_out, int out_size, void* d_ws, size_t ws_size,
                              hipStream_t stream) {
    const float* x       = (const float*)d_in[0];
    const float* dconv_w = (const float*)d_in[1];
    const float* dconv_b = (const float*)d_in[2];
    const float* off_w   = (const float*)d_in[3];
    const float* off_b   = (const float*)d_in[4];
    const float* def_w   = (const float*)d_in[5];
    const float* def_b   = (const float*)d_in[6];
    float* out = (float*)d_out;

    char* ws = (char*)d_ws;
    short* xb16 = (short*)(ws);
    short* x3b  = (short*)(ws + 12582912);
    short* wB1  = (short*)(ws + 25165824);
    short* wB2  = (short*)(ws + 25331712);
    short* wB   = (short*)(ws + 25387008);

    k_repack<<<324, 256, 0, stream>>>(dconv_w, off_w, def_w, wB1, wB2, wB);
    k_transpose<<<(BD*HWD)/256, 256, 0, stream>>>(x, xb16);
    k_conv1<<<(BD*HWD)/64, 256, 0, stream>>>(x, xb16, wB1, dconv_b, x3b);
    k_deform<<<(BD*HWD)/64, 256, 0, stream>>>(x3b, wB2, off_b, wB, def_b, out);
}

// Round 8
// 173.750 us; speedup vs baseline: 8.1408x; 1.1328x over previous
//
#include <hip/hip_runtime.h>
#include <hip/hip_bf16.h>

#define BD 4
#define CD 96
#define OD 96
#define HD 128
#define WD 128
#define HWD (HD*WD)          // 16384

typedef __attribute__((ext_vector_type(8))) short bfrag;   // 8 bf16 (4 VGPRs)
typedef __attribute__((ext_vector_type(4))) float ffrag;   // 4 fp32 acc

__device__ __forceinline__ short f2bs(float f) {
    __hip_bfloat16 h = __float2bfloat16(f);
    return *reinterpret_cast<short*>(&h);
}

// XCD-aware swizzle for 512-block launches (round-robin dispatch over 8 XCDs):
// XCD k owns 64 consecutive logical blocks = 64 image rows -> tap/gather halos
// stay in its 4 MiB L2, and conv1's x3b band is re-read by the same XCD.
__device__ __forceinline__ int swizzle512(int gid) {
    return ((gid & 7) << 6) | (gid >> 3);
}

// ---------------------------------------------------------------------------
// Transpose: x (NCHW fp32) -> xb16 (pixel-major NHWC bf16)
// ---------------------------------------------------------------------------
__global__ __launch_bounds__(256) void k_transpose(const float* __restrict__ x,
                                                   short* __restrict__ xb16) {
    __shared__ short tile[256 * 104];
    int pix0 = blockIdx.x * 256;
    int b = pix0 / HWD; int hw0 = pix0 % HWD;
    int tid = threadIdx.x;

    for (int e = tid; e < 96*64; e += 256) {
        int c = e >> 6, g = e & 63;
        float4 v = *(const float4*)(x + ((size_t)(b*96 + c))*HWD + hw0 + 4*g);
        tile[(4*g+0)*104 + c] = f2bs(v.x);
        tile[(4*g+1)*104 + c] = f2bs(v.y);
        tile[(4*g+2)*104 + c] = f2bs(v.z);
        tile[(4*g+3)*104 + c] = f2bs(v.w);
    }
    __syncthreads();
    for (int e = tid; e < 256*12; e += 256) {
        int px = e / 12, c8 = e % 12;
        bfrag v = *(const bfrag*)(tile + px*104 + c8*8);
        *(bfrag*)(xb16 + ((size_t)(pix0 + px))*96 + c8*8) = v;
    }
}

// ---------------------------------------------------------------------------
// Repack weights to bf16 MFMA B-frag layouts (k = tap*96 + c):
//   wB1 (864x96): dconv_w   wB2 (864x32, o<18): off_w   wB (864x96): def_w
//   order: w[((s*NT+nt)*64 + l)*8 + j] = B[k=32s+(l>>4)*8+j][o=16nt+(l&15)]
// ---------------------------------------------------------------------------
__global__ void k_repack(const float* __restrict__ dconv_w,
                         const float* __restrict__ off_w,
                         const float* __restrict__ def_w,
                         short* __restrict__ wB1,
                         short* __restrict__ wB2,
                         short* __restrict__ wB) {
    int t = blockIdx.x * blockDim.x + threadIdx.x;
    if (t < 27648) {              // 864 x 32, NT=2
        int j = t & 7; int l = (t >> 3) & 63; int tile = t >> 9;
        int s = tile >> 1, nt = tile & 1;
        int k = 32*s + (l >> 4)*8 + j;
        int o = 16*nt + (l & 15);
        int c = k % 96, tap = k / 96;
        wB2[t] = (o < 18) ? f2bs(off_w[(o*96 + c)*9 + tap]) : (short)0;
    }
    if (t < 82944) {              // 864 x 96, NT=6
        int j = t & 7; int l = (t >> 3) & 63; int tile = t >> 9;
        int s = tile / 6, nt = tile % 6;
        int k = 32*s + (l >> 4)*8 + j;
        int o = 16*nt + (l & 15);
        int c = k % 96, tap = k / 96;
        wB1[t] = f2bs(dconv_w[(o*96 + c)*9 + tap]);
        wB[t]  = f2bs(def_w [(o*96 + c)*9 + tap]);
    }
}

// ---------------------------------------------------------------------------
// Kernel 1 (M=32/wave MFMA): x3b = bf16(x + relu(conv3x3 dil2 pad2(x))), NHWC
// Block = 1 image row (128 px), 4 waves; wave owns 32 px as two 16-px m-tiles
// sharing every B-fragment (halves per-pixel weight traffic).
// ---------------------------------------------------------------------------
__global__ __launch_bounds__(256, 2) void k_conv1(const float* __restrict__ x,
                                                  const short* __restrict__ xb16,
                                                  const short* __restrict__ wB,
                                                  const float* __restrict__ bias,
                                                  short* __restrict__ x3b) {
    int pix0 = swizzle512(blockIdx.x) * 128;
    int b = pix0 / HWD; int hw0 = pix0 % HWD;
    int h = hw0 / WD;                      // block = full row, w0 == 0
    int tid = threadIdx.x;
    int l = tid & 63, wv = tid >> 6;
    int q = l >> 4, mr = l & 15;
    int wq = 32*wv;
    const short* xb = xb16 + ((size_t)b * HWD) * 96;
    const bfrag az = {0,0,0,0,0,0,0,0};

    ffrag acc[2][6];
    #pragma unroll
    for (int mt = 0; mt < 2; mt++)
        #pragma unroll
        for (int nt = 0; nt < 6; nt++) acc[mt][nt] = ffrag{0.f,0.f,0.f,0.f};

    #pragma unroll 1
    for (int tap = 0; tap < 9; tap++) {
        int y = h + (tap/3)*2 - 2;
        if ((unsigned)y >= HD) continue;
        const short* abase[2]; bool vx[2];
        #pragma unroll
        for (int mt = 0; mt < 2; mt++) {
            int xx = wq + 16*mt + mr + (tap%3)*2 - 2;
            int xxc = min(max(xx, 0), WD-1);
            vx[mt] = (unsigned)xx < WD;
            abase[mt] = xb + ((size_t)(y*WD + xxc))*96 + q*8;
        }
        #pragma unroll
        for (int sc = 0; sc < 3; sc++) {
            const short* wb = wB + ((size_t)((tap*3+sc)*6)*64 + l)*8;
            bfrag bb[6];
            #pragma unroll
            for (int nt = 0; nt < 6; nt++) bb[nt] = *(const bfrag*)(wb + nt*512);
            #pragma unroll
            for (int mt = 0; mt < 2; mt++) {
                bfrag a = *(const bfrag*)(abase[mt] + sc*32);
                if (!vx[mt]) a = az;
                #pragma unroll
                for (int nt = 0; nt < 6; nt++)
                    acc[mt][nt] = __builtin_amdgcn_mfma_f32_16x16x32_bf16(a, bb[nt], acc[mt][nt], 0, 0, 0);
            }
        }
    }

    #pragma unroll
    for (int mt = 0; mt < 2; mt++) {
        int hwb = hw0 + wq + 16*mt + q*4;
        #pragma unroll
        for (int nt = 0; nt < 6; nt++) {
            int o = 16*nt + mr;
            float bo = bias[o];
            float4 xr = *(const float4*)(x + ((size_t)(b*96 + o))*HWD + hwb);
            short* op = x3b + ((size_t)(b*HWD + hwb))*96 + o;
            op[0]   = f2bs(xr.x + fmaxf(acc[mt][nt][0] + bo, 0.f));
            op[96]  = f2bs(xr.y + fmaxf(acc[mt][nt][1] + bo, 0.f));
            op[192] = f2bs(xr.z + fmaxf(acc[mt][nt][2] + bo, 0.f));
            op[288] = f2bs(xr.w + fmaxf(acc[mt][nt][3] + bo, 0.f));
        }
    }
}

// ---------------------------------------------------------------------------
// Kernel 2 (fused, M=32/wave): conv2-MFMA -> offsets (10KB LDS, no barriers)
// -> bilinear gather (registers) -> deform MFMA (B-frags shared across the
// two m-tiles) -> out.
// ---------------------------------------------------------------------------
__global__ __launch_bounds__(256, 2) void k_deform(const short* __restrict__ x3b,
                                                   const short* __restrict__ wB2,
                                                   const float* __restrict__ off_b,
                                                   const short* __restrict__ wB,
                                                   const float* __restrict__ def_b,
                                                   float* __restrict__ out) {
    __shared__ float offsb[128][20];

    int pix0 = swizzle512(blockIdx.x) * 128;
    int b = pix0 / HWD; int hw0 = pix0 % HWD;
    int h = hw0 / WD;                      // block = full row, w0 == 0
    int tid = threadIdx.x;
    int l = tid & 63, wv = tid >> 6;
    int q = l >> 4, mr = l & 15;
    int wq = 32*wv;
    const short* xb = x3b + ((size_t)b * HWD) * 96;
    const bfrag az = {0,0,0,0,0,0,0,0};

    // ---- conv2 via MFMA: offsets for this wave's 32 pixels ----
    ffrag oa[2][2];
    #pragma unroll
    for (int mt = 0; mt < 2; mt++)
        #pragma unroll
        for (int nt = 0; nt < 2; nt++) oa[mt][nt] = ffrag{0.f,0.f,0.f,0.f};

    #pragma unroll 1
    for (int tap = 0; tap < 9; tap++) {
        int y = h + tap/3 - 1;
        if ((unsigned)y >= HD) continue;
        const short* abase[2]; bool vx[2];
        #pragma unroll
        for (int mt = 0; mt < 2; mt++) {
            int xx = wq + 16*mt + mr + tap%3 - 1;
            int xxc = min(max(xx, 0), WD-1);
            vx[mt] = (unsigned)xx < WD;
            abase[mt] = xb + ((size_t)(y*WD + xxc))*96 + q*8;
        }
        #pragma unroll
        for (int sc = 0; sc < 3; sc++) {
            const short* wb = wB2 + ((size_t)((tap*3+sc)*2)*64 + l)*8;
            bfrag b0 = *(const bfrag*)(wb);
            bfrag b1 = *(const bfrag*)(wb + 512);
            #pragma unroll
            for (int mt = 0; mt < 2; mt++) {
                bfrag a = *(const bfrag*)(abase[mt] + sc*32);
                if (!vx[mt]) a = az;
                oa[mt][0] = __builtin_amdgcn_mfma_f32_16x16x32_bf16(a, b0, oa[mt][0], 0, 0, 0);
                oa[mt][1] = __builtin_amdgcn_mfma_f32_16x16x32_bf16(a, b1, oa[mt][1], 0, 0, 0);
            }
        }
    }
    #pragma unroll
    for (int mt = 0; mt < 2; mt++) {
        int row = wq + 16*mt + q*4;
        float bo0 = off_b[mr];
        #pragma unroll
        for (int r = 0; r < 4; r++) offsb[row + r][mr] = oa[mt][0][r] + bo0;
        if (mr < 2) {
            float bo1 = off_b[16 + mr];
            #pragma unroll
            for (int r = 0; r < 4; r++) offsb[row + r][16 + mr] = oa[mt][1][r] + bo1;
        }
    }
    // no __syncthreads: offsb rows wq..wq+31 produced & consumed by wave wv

    // ---- gather + deform MFMA ----
    ffrag acc[2][6];
    #pragma unroll
    for (int mt = 0; mt < 2; mt++)
        #pragma unroll
        for (int nt = 0; nt < 6; nt++) acc[mt][nt] = ffrag{0.f,0.f,0.f,0.f};

    #pragma unroll 1
    for (int tap = 0; tap < 9; tap++) {
        const short* pp[2][4];
        float fb[2][4];
        #pragma unroll
        for (int mt = 0; mt < 2; mt++) {
            int w = wq + 16*mt + mr;
            float dy = offsb[w][2*tap];
            float dx = offsb[w][2*tap + 1];
            float py  = (float)(h + tap/3 - 1) + dy;
            float pxf = (float)(w + tap%3 - 1) + dx;
            float y0f = floorf(py), x0f = floorf(pxf);
            float wy = py - y0f, wx = pxf - x0f;
            int y0 = (int)y0f, x0 = (int)x0f;
            int y1 = y0 + 1, x1 = x0 + 1;
            bool vy0 = (unsigned)y0 < HD, vy1 = (unsigned)y1 < HD;
            bool vx0 = (unsigned)x0 < WD, vx1 = (unsigned)x1 < WD;
            fb[mt][0] = (vy0 && vx0) ? (1.f-wy)*(1.f-wx) : 0.f;
            fb[mt][1] = (vy0 && vx1) ? (1.f-wy)*wx       : 0.f;
            fb[mt][2] = (vy1 && vx0) ? wy*(1.f-wx)       : 0.f;
            fb[mt][3] = (vy1 && vx1) ? wy*wx             : 0.f;
            int yc0 = min(max(y0,0),HD-1), yc1 = min(max(y1,0),HD-1);
            int xc0 = min(max(x0,0),WD-1), xc1 = min(max(x1,0),WD-1);
            pp[mt][0] = xb + ((size_t)(yc0*WD + xc0))*96 + q*8;
            pp[mt][1] = xb + ((size_t)(yc0*WD + xc1))*96 + q*8;
            pp[mt][2] = xb + ((size_t)(yc1*WD + xc0))*96 + q*8;
            pp[mt][3] = xb + ((size_t)(yc1*WD + xc1))*96 + q*8;
        }
        #pragma unroll
        for (int sc = 0; sc < 3; sc++) {
            int s = tap*3 + sc;
            const short* wb = wB + ((size_t)(s*6)*64 + l)*8;
            bfrag bbf[6];
            #pragma unroll
            for (int nt = 0; nt < 6; nt++) bbf[nt] = *(const bfrag*)(wb + nt*512);
            #pragma unroll
            for (int mt = 0; mt < 2; mt++) {
                bfrag c00 = *(const bfrag*)(pp[mt][0] + sc*32);
                bfrag c01 = *(const bfrag*)(pp[mt][1] + sc*32);
                bfrag c10 = *(const bfrag*)(pp[mt][2] + sc*32);
                bfrag c11 = *(const bfrag*)(pp[mt][3] + sc*32);
                const int* i00 = (const int*)&c00;
                const int* i01 = (const int*)&c01;
                const int* i10 = (const int*)&c10;
                const int* i11 = (const int*)&c11;
                float f00 = fb[mt][0], f01 = fb[mt][1];
                float f10 = fb[mt][2], f11 = fb[mt][3];
                int ap[4];
                #pragma unroll
                for (int d = 0; d < 4; d++) {
                    float a0 = __int_as_float(((unsigned)i00[d]) << 16);
                    float b0f = __int_as_float(((unsigned)i01[d]) << 16);
                    float c0f = __int_as_float(((unsigned)i10[d]) << 16);
                    float d0 = __int_as_float(((unsigned)i11[d]) << 16);
                    float a1 = __int_as_float(i00[d] & 0xffff0000);
                    float b1f = __int_as_float(i01[d] & 0xffff0000);
                    float c1f = __int_as_float(i10[d] & 0xffff0000);
                    float d1 = __int_as_float(i11[d] & 0xffff0000);
                    float rlo = f00*a0 + f01*b0f + f10*c0f + f11*d0;
                    float rhi = f00*a1 + f01*b1f + f10*c1f + f11*d1;
                    ap[d] = (int)((unsigned short)f2bs(rlo)) |
                            ((int)((unsigned short)f2bs(rhi)) << 16);
                }
                bfrag a = *(const bfrag*)ap;
                #pragma unroll
                for (int nt = 0; nt < 6; nt++)
                    acc[mt][nt] = __builtin_amdgcn_mfma_f32_16x16x32_bf16(a, bbf[nt], acc[mt][nt], 0, 0, 0);
            }
        }
    }

    // ---- epilogue: NCHW fp32 out, float4 per (m-tile, n-tile) ----
    #pragma unroll
    for (int mt = 0; mt < 2; mt++) {
        int hwb = hw0 + wq + 16*mt + q*4;
        #pragma unroll
        for (int nt = 0; nt < 6; nt++) {
            int o = 16*nt + mr;
            float bo = def_b[o];
            float4 v;
            v.x = acc[mt][nt][0] + bo; v.y = acc[mt][nt][1] + bo;
            v.z = acc[mt][nt][2] + bo; v.w = acc[mt][nt][3] + bo;
            *(float4*)(out + ((size_t)(b*96 + o))*HWD + hwb) = v;
        }
    }
}

// ---------------------------------------------------------------------------
// Workspace layout (bytes):
//   xb16 : 0        .. 12582912   (B*HW*96 bf16, NHWC of x)
//   x3b  : 12582912 .. 25165824   (B*HW*96 bf16, NHWC of x3)
//   wB1  : 25165824 .. 25331712
//   wB2  : 25331712 .. 25387008
//   wB   : 25387008 .. 25552896
// ---------------------------------------------------------------------------
extern "C" void kernel_launch(void* const* d_in, const int* in_sizes, int n_in,
                              void* d_out, int out_size, void* d_ws, size_t ws_size,
                              hipStream_t stream) {
    const float* x       = (const float*)d_in[0];
    const float* dconv_w = (const float*)d_in[1];
    const float* dconv_b = (const float*)d_in[2];
    const float* off_w   = (const float*)d_in[3];
    const float* off_b   = (const float*)d_in[4];
    const float* def_w   = (const float*)d_in[5];
    const float* def_b   = (const float*)d_in[6];
    float* out = (float*)d_out;

    char* ws = (char*)d_ws;
    short* xb16 = (short*)(ws);
    short* x3b  = (short*)(ws + 12582912);
    short* wB1  = (short*)(ws + 25165824);
    short* wB2  = (short*)(ws + 25331712);
    short* wB   = (short*)(ws + 25387008);

    k_repack<<<324, 256, 0, stream>>>(dconv_w, off_w, def_w, wB1, wB2, wB);
    k_transpose<<<(BD*HWD)/256, 256, 0, stream>>>(x, xb16);
    k_conv1<<<(BD*HWD)/128, 256, 0, stream>>>(x, xb16, wB1, dconv_b, x3b);
    k_deform<<<(BD*HWD)/128, 256, 0, stream>>>(x3b, wB2, off_b, wB, def_b, out);
}